// Round 6
// baseline (4724.420 us; speedup 1.0000x reference)
//
#include <hip/hip_runtime.h>
#include <hip/hip_bf16.h>
#include <math.h>

#define LAG   8192
#define NROW  32768        // LAG * 4 tweets
#define DIMD  1024

typedef __attribute__((ext_vector_type(8))) short  short8;   // 8 bf16 (4 VGPRs)
typedef __attribute__((ext_vector_type(4))) float  f32x4;    // mfma acc
typedef __attribute__((ext_vector_type(2))) float  f32x2;
typedef unsigned short ushort_t;
typedef unsigned int   uint_t;

// fp32 -> packed (bf16 hi | bf16 lo << 16), RNE both. f ~= hi + lo (err ~2^-18*f)
__device__ __forceinline__ uint_t split2_pack(float f) {
    unsigned u = __float_as_uint(f);
    unsigned r = u + 0x7FFFu + ((u >> 16) & 1u);
    unsigned h = r >> 16;
    float hf = __uint_as_float(h << 16);
    float lf = f - hf;
    unsigned u2 = __float_as_uint(lf);
    unsigned r2 = u2 + 0x7FFFu + ((u2 >> 16) & 1u);
    return h | (r2 & 0xFFFF0000u);
}
// packed -> fp32 value
__device__ __forceinline__ float updp(uint_t p) {
    return __uint_as_float(p << 16) + __uint_as_float(p & 0xFFFF0000u);
}
// separate planes -> fp32 value
__device__ __forceinline__ float up2(ushort_t h, ushort_t l) {
    return __uint_as_float((uint_t)h << 16) + __uint_as_float((uint_t)l << 16);
}

// unpack 16 packed uints -> hi-plane 16B x2 and lo-plane 16B x2 (fallback path)
__device__ __forceinline__ void unpack16(const uint_t* r, uint4& h0, uint4& h1,
                                         uint4& l0, uint4& l1) {
    h0.x = __builtin_amdgcn_perm(r[1],  r[0],  0x05040100u);
    h0.y = __builtin_amdgcn_perm(r[3],  r[2],  0x05040100u);
    h0.z = __builtin_amdgcn_perm(r[5],  r[4],  0x05040100u);
    h0.w = __builtin_amdgcn_perm(r[7],  r[6],  0x05040100u);
    h1.x = __builtin_amdgcn_perm(r[9],  r[8],  0x05040100u);
    h1.y = __builtin_amdgcn_perm(r[11], r[10], 0x05040100u);
    h1.z = __builtin_amdgcn_perm(r[13], r[12], 0x05040100u);
    h1.w = __builtin_amdgcn_perm(r[15], r[14], 0x05040100u);
    l0.x = __builtin_amdgcn_perm(r[1],  r[0],  0x07060302u);
    l0.y = __builtin_amdgcn_perm(r[3],  r[2],  0x07060302u);
    l0.z = __builtin_amdgcn_perm(r[5],  r[4],  0x07060302u);
    l0.w = __builtin_amdgcn_perm(r[7],  r[6],  0x07060302u);
    l1.x = __builtin_amdgcn_perm(r[9],  r[8],  0x07060302u);
    l1.y = __builtin_amdgcn_perm(r[11], r[10], 0x07060302u);
    l1.z = __builtin_amdgcn_perm(r[13], r[12], 0x07060302u);
    l1.w = __builtin_amdgcn_perm(r[15], r[14], 0x07060302u);
}

// ============================================================================
// gemm8: 256x256-tile deep-pipelined bf16x3 GEMM,  C[M,1024] = act(A@B + bias)
// Inputs: A as separate hi/lo bf16 planes [M][1024]; B as TRANSPOSED planes
// Bt[n][k] (hi/lo). Split product = single bf16 GEMM over K=3072 in 3 segments:
//   seg0 (Ah,Bh), seg1 (Ah,Bl), seg2 (Al,Bh)   -> hh + hl + lh ~ fp32 accuracy.
// 512 thr (8 waves, 2M x 4N), per-wave out 128x64 (8x4 16x16x32 mfma frags).
// LDS 128 KiB: 2 buf x 4 regions [128 rows][64 k] bf16, XOR-swizzled
// (chunk ^= row&7 on 16B chunks) -> uniform banks on ds_read_b128.
// Pipeline: reg-staged (global->VGPR->ds_write). Per tile t:
//   raw s_barrier; ds_write tile t+1 -> buf[1-b]; global_load tile t+2 -> regs;
//   24 ds_read + 64 MFMA on buf[b]; lgkmcnt(0); barrier.
// Loads stay in flight across barriers (no vmcnt(0) drain -> escapes the ~900TF
// 2-barrier ceiling, m97/m218). WAR-safe: writes only touch the non-read buffer.
// Grid must be (4, M/256); bijective XCD swizzle via gridDim.y.
// ============================================================================
#define NT8 48

template<int CM, bool BIAS, bool RELU>
__global__ __launch_bounds__(512, 2) void gemm8(
    const ushort_t* __restrict__ Ah, const ushort_t* __restrict__ Al,
    const ushort_t* __restrict__ Bth, const ushort_t* __restrict__ Btl,
    const float* __restrict__ bias,
    float* __restrict__ Cf, ushort_t* __restrict__ Ch, ushort_t* __restrict__ Cl)
{
    __shared__ ushort_t lds8[65536];    // 2 buf x 4 regions x 8192 ushorts = 128 KiB
    const int tid  = threadIdx.x;
    const int lane = tid & 63;
    const int wave = tid >> 6;
    const int wr   = wave >> 2;         // 0..1 (M)
    const int wc   = wave & 3;          // 0..3 (N)
    const int ln15 = lane & 15;
    const int g    = lane >> 4;

    const int lin  = blockIdx.y * 4 + blockIdx.x;
    const int cpx  = gridDim.y >> 1;    // nwg/8
    const int swz  = (lin & 7) * cpx + (lin >> 3);
    const int row0 = (swz >> 2) * 256;
    const int col0 = (swz & 3) * 256;

    // staging coords: thread covers 16B chunk (sr, sch) and (sr+64, sch)
    const int sr   = tid >> 3;          // 0..63
    const int sch  = tid & 7;
    const int woff0 = sr * 64 + ((sch ^ (sr & 7)) * 8);   // ushorts, swizzled
    // fragment swizzled chunk offsets (rr&7 == ln15&7)
    const int fx0 = ((g)     ^ (ln15 & 7)) * 8;           // ksub 0
    const int fx1 = ((4 + g) ^ (ln15 & 7)) * 8;           // ksub 1

    f32x4 acc[8][4] = {};
    uint4 st[4][2];

#define G8_LOAD(tt)                                                             \
    {                                                                           \
        const int seg_ = (tt) >> 4;                                             \
        const int ko_  = ((tt) & 15) * 64;                                      \
        const ushort_t* ap_ = (seg_ == 2) ? Al  : Ah;                           \
        const ushort_t* bp_ = (seg_ == 1) ? Btl : Bth;                          \
        st[0][0] = *(const uint4*)(ap_ + (size_t)(row0 +       sr) * DIMD + ko_ + sch * 8); \
        st[0][1] = *(const uint4*)(ap_ + (size_t)(row0 +  64 + sr) * DIMD + ko_ + sch * 8); \
        st[1][0] = *(const uint4*)(ap_ + (size_t)(row0 + 128 + sr) * DIMD + ko_ + sch * 8); \
        st[1][1] = *(const uint4*)(ap_ + (size_t)(row0 + 192 + sr) * DIMD + ko_ + sch * 8); \
        st[2][0] = *(const uint4*)(bp_ + (size_t)(col0 +       sr) * DIMD + ko_ + sch * 8); \
        st[2][1] = *(const uint4*)(bp_ + (size_t)(col0 +  64 + sr) * DIMD + ko_ + sch * 8); \
        st[3][0] = *(const uint4*)(bp_ + (size_t)(col0 + 128 + sr) * DIMD + ko_ + sch * 8); \
        st[3][1] = *(const uint4*)(bp_ + (size_t)(col0 + 192 + sr) * DIMD + ko_ + sch * 8); \
    }
#define G8_WRITE(bb)                                                            \
    {                                                                           \
        ushort_t* d_ = lds8 + (bb) * 32768;                                     \
        *(uint4*)&d_[0 * 8192 + woff0]        = st[0][0];                       \
        *(uint4*)&d_[0 * 8192 + woff0 + 4096] = st[0][1];                       \
        *(uint4*)&d_[1 * 8192 + woff0]        = st[1][0];                       \
        *(uint4*)&d_[1 * 8192 + woff0 + 4096] = st[1][1];                       \
        *(uint4*)&d_[2 * 8192 + woff0]        = st[2][0];                       \
        *(uint4*)&d_[2 * 8192 + woff0 + 4096] = st[2][1];                       \
        *(uint4*)&d_[3 * 8192 + woff0]        = st[3][0];                       \
        *(uint4*)&d_[3 * 8192 + woff0 + 4096] = st[3][1];                       \
    }

    // prologue: tile 0 staged+written, tile 1 staged in regs
    G8_LOAD(0);
    G8_WRITE(0);
    G8_LOAD(1);
    asm volatile("s_waitcnt lgkmcnt(0)" ::: "memory");
    __builtin_amdgcn_s_barrier();
    __builtin_amdgcn_sched_barrier(0);

    for (int t = 0; t < NT8; ++t) {
        const int b = t & 1;
        if (t + 1 < NT8) G8_WRITE(1 - b);     // regs hold tile t+1
        if (t + 2 < NT8) G8_LOAD(t + 2);      // issue next loads early

        const ushort_t* Lb = lds8 + b * 32768;
        short8 af[4][2], bf0[2][2], bf1[2][2];
        // B nh0 (region 2) + A mh0 (region 0)
        #pragma unroll
        for (int i = 0; i < 4; ++i) {
            int rr = (2 * i + wr) * 16 + ln15;
            af[i][0] = *(const short8*)&Lb[rr * 64 + fx0];
            af[i][1] = *(const short8*)&Lb[rr * 64 + fx1];
        }
        #pragma unroll
        for (int j = 0; j < 2; ++j) {
            int rr = (4 * j + wc) * 16 + ln15;
            bf0[j][0] = *(const short8*)&Lb[2 * 8192 + rr * 64 + fx0];
            bf0[j][1] = *(const short8*)&Lb[2 * 8192 + rr * 64 + fx1];
        }
        __builtin_amdgcn_s_setprio(1);
        #pragma unroll
        for (int i = 0; i < 4; ++i)
            #pragma unroll
            for (int j = 0; j < 2; ++j) {
                acc[i][j] = __builtin_amdgcn_mfma_f32_16x16x32_bf16(af[i][0], bf0[j][0], acc[i][j], 0, 0, 0);
                acc[i][j] = __builtin_amdgcn_mfma_f32_16x16x32_bf16(af[i][1], bf0[j][1], acc[i][j], 0, 0, 0);
            }
        __builtin_amdgcn_s_setprio(0);
        // B nh1 (region 3)
        #pragma unroll
        for (int j = 0; j < 2; ++j) {
            int rr = (4 * j + wc) * 16 + ln15;
            bf1[j][0] = *(const short8*)&Lb[3 * 8192 + rr * 64 + fx0];
            bf1[j][1] = *(const short8*)&Lb[3 * 8192 + rr * 64 + fx1];
        }
        __builtin_amdgcn_s_setprio(1);
        #pragma unroll
        for (int i = 0; i < 4; ++i)
            #pragma unroll
            for (int j = 0; j < 2; ++j) {
                acc[i][2 + j] = __builtin_amdgcn_mfma_f32_16x16x32_bf16(af[i][0], bf1[j][0], acc[i][2 + j], 0, 0, 0);
                acc[i][2 + j] = __builtin_amdgcn_mfma_f32_16x16x32_bf16(af[i][1], bf1[j][1], acc[i][2 + j], 0, 0, 0);
            }
        __builtin_amdgcn_s_setprio(0);
        // A mh1 (region 1)
        #pragma unroll
        for (int i = 0; i < 4; ++i) {
            int rr = (2 * i + wr) * 16 + ln15;
            af[i][0] = *(const short8*)&Lb[1 * 8192 + rr * 64 + fx0];
            af[i][1] = *(const short8*)&Lb[1 * 8192 + rr * 64 + fx1];
        }
        __builtin_amdgcn_s_setprio(1);
        #pragma unroll
        for (int i = 0; i < 4; ++i)
            #pragma unroll
            for (int j = 0; j < 2; ++j) {
                acc[4 + i][j] = __builtin_amdgcn_mfma_f32_16x16x32_bf16(af[i][0], bf0[j][0], acc[4 + i][j], 0, 0, 0);
                acc[4 + i][j] = __builtin_amdgcn_mfma_f32_16x16x32_bf16(af[i][1], bf0[j][1], acc[4 + i][j], 0, 0, 0);
            }
        #pragma unroll
        for (int i = 0; i < 4; ++i)
            #pragma unroll
            for (int j = 0; j < 2; ++j) {
                acc[4 + i][2 + j] = __builtin_amdgcn_mfma_f32_16x16x32_bf16(af[i][0], bf1[j][0], acc[4 + i][2 + j], 0, 0, 0);
                acc[4 + i][2 + j] = __builtin_amdgcn_mfma_f32_16x16x32_bf16(af[i][1], bf1[j][1], acc[4 + i][2 + j], 0, 0, 0);
            }
        __builtin_amdgcn_s_setprio(0);

        asm volatile("s_waitcnt lgkmcnt(0)" ::: "memory");
        __builtin_amdgcn_sched_barrier(0);
        __builtin_amdgcn_s_barrier();
        __builtin_amdgcn_sched_barrier(0);
    }
#undef G8_LOAD
#undef G8_WRITE

    // epilogue: C/D layout col=lane&15, row=(lane>>4)*4+reg (m89-verified)
    #pragma unroll
    for (int J = 0; J < 4; ++J) {
        const int col = col0 + ((J >> 1) * 8 + (J & 1) * 4 + wc) * 16 + ln15;
        float bv = 0.f;
        if constexpr (BIAS) bv = bias[col];
        #pragma unroll
        for (int I = 0; I < 8; ++I) {
            const int srow = (I >> 2) * 8 + 2 * (I & 3) + wr;
            #pragma unroll
            for (int r = 0; r < 4; ++r) {
                const int row = row0 + srow * 16 + g * 4 + r;
                float v = acc[I][J][r] + bv;
                if constexpr (RELU) v = fmaxf(v, 0.f);
                if constexpr (CM == 0) {
                    Cf[(size_t)row * DIMD + col] = v;
                } else {
                    uint_t p = split2_pack(v);
                    Ch[(size_t)row * DIMD + col] = (ushort_t)(p & 0xFFFFu);
                    Cl[(size_t)row * DIMD + col] = (ushort_t)(p >> 16);
                }
            }
        }
    }
}

// ============================================================================
// OLD bf16x3 split MFMA GEMM (128x128) -- retained for small-workspace fallback
// ============================================================================
template<int BM, int CM, bool BIAS, bool RELU>
__global__ __launch_bounds__(256) void mgemm(
    const uint_t* __restrict__ Apk, const void* __restrict__ Bsrc,
    const float* __restrict__ bias,
    float* __restrict__ Cf, uint_t* __restrict__ Cp)
{
    __shared__ ushort_t As_h[128*40], As_l[128*40], Bs_h[128*40], Bs_l[128*40];
    const int tid  = threadIdx.x;
    const int lane = tid & 63;
    const int wave = tid >> 6;
    const int wm   = (wave & 1) * 64;
    const int wn   = (wave >> 1) * 64;
    const int ln15 = lane & 15;
    const int q8   = (lane >> 4) * 8;
    const int lin  = blockIdx.y * 8 + blockIdx.x;
    const int swz  = (lin & 7) * gridDim.y + (lin >> 3);
    const int row0 = (swz >> 3) * 128;
    const int col0 = (swz & 7) * 128;

    const int ar  = tid >> 1;
    const int ako = (tid & 1) << 4;
    const int bn  = tid & 127;
    const int bk  = (tid >> 7) << 4;

    f32x4 acc[4][4] = {};

    uint_t a_r[16] __attribute__((aligned(16)));
    uint_t b_r[16] __attribute__((aligned(16)));

    {
        const uint_t* Apt = Apk + (size_t)(row0 + ar) * DIMD + ako;
        *(uint4*)&a_r[0]  = *(const uint4*)(Apt + 0);
        *(uint4*)&a_r[4]  = *(const uint4*)(Apt + 4);
        *(uint4*)&a_r[8]  = *(const uint4*)(Apt + 8);
        *(uint4*)&a_r[12] = *(const uint4*)(Apt + 12);
        if constexpr (BM == 1) {
            const uint_t* Bpt = (const uint_t*)Bsrc + (size_t)bk * DIMD + col0 + bn;
            #pragma unroll
            for (int i = 0; i < 16; ++i) b_r[i] = Bpt[(size_t)i * DIMD];
        } else {
            const float* Bpt = (const float*)Bsrc + (size_t)bk * DIMD + col0 + bn;
            #pragma unroll
            for (int i = 0; i < 16; ++i) b_r[i] = split2_pack(Bpt[(size_t)i * DIMD]);
        }
    }

    for (int k0 = 0; k0 < DIMD; k0 += 32) {
        __syncthreads();
        {
            uint4 h0, h1, l0, l1;
            unpack16(a_r, h0, h1, l0, l1);
            *(uint4*)&As_h[ar*40 + ako]     = h0;
            *(uint4*)&As_h[ar*40 + ako + 8] = h1;
            *(uint4*)&As_l[ar*40 + ako]     = l0;
            *(uint4*)&As_l[ar*40 + ako + 8] = l1;
            unpack16(b_r, h0, h1, l0, l1);
            *(uint4*)&Bs_h[bn*40 + bk]      = h0;
            *(uint4*)&Bs_h[bn*40 + bk + 8]  = h1;
            *(uint4*)&Bs_l[bn*40 + bk]      = l0;
            *(uint4*)&Bs_l[bn*40 + bk + 8]  = l1;
        }
        __syncthreads();

        if (k0 + 32 < DIMD) {
            const int kn = k0 + 32;
            const uint_t* Apt = Apk + (size_t)(row0 + ar) * DIMD + kn + ako;
            *(uint4*)&a_r[0]  = *(const uint4*)(Apt + 0);
            *(uint4*)&a_r[4]  = *(const uint4*)(Apt + 4);
            *(uint4*)&a_r[8]  = *(const uint4*)(Apt + 8);
            *(uint4*)&a_r[12] = *(const uint4*)(Apt + 12);
            if constexpr (BM == 1) {
                const uint_t* Bpt = (const uint_t*)Bsrc + (size_t)(kn + bk) * DIMD + col0 + bn;
                #pragma unroll
                for (int i = 0; i < 16; ++i) b_r[i] = Bpt[(size_t)i * DIMD];
            } else {
                const float* Bpt = (const float*)Bsrc + (size_t)(kn + bk) * DIMD + col0 + bn;
                #pragma unroll
                for (int i = 0; i < 16; ++i) b_r[i] = split2_pack(Bpt[(size_t)i * DIMD]);
            }
        }

        short8 fah[4], fal[4];
        #pragma unroll
        for (int i = 0; i < 4; ++i) {
            fah[i] = *(const short8*)&As_h[(wm + 16*i + ln15)*40 + q8];
            fal[i] = *(const short8*)&As_l[(wm + 16*i + ln15)*40 + q8];
        }
        #pragma unroll
        for (int j = 0; j < 4; ++j) {
            short8 fbh = *(const short8*)&Bs_h[(wn + 16*j + ln15)*40 + q8];
            short8 fbl = *(const short8*)&Bs_l[(wn + 16*j + ln15)*40 + q8];
            #pragma unroll
            for (int i = 0; i < 4; ++i) {
                acc[i][j] = __builtin_amdgcn_mfma_f32_16x16x32_bf16(fal[i], fbh, acc[i][j], 0, 0, 0);
                acc[i][j] = __builtin_amdgcn_mfma_f32_16x16x32_bf16(fah[i], fbl, acc[i][j], 0, 0, 0);
                acc[i][j] = __builtin_amdgcn_mfma_f32_16x16x32_bf16(fah[i], fbh, acc[i][j], 0, 0, 0);
            }
        }
    }

    #pragma unroll
    for (int j = 0; j < 4; ++j) {
        const int col = col0 + wn + 16*j + ln15;
        float bv = 0.f;
        if constexpr (BIAS) bv = bias[col];
        #pragma unroll
        for (int i = 0; i < 4; ++i) {
            #pragma unroll
            for (int r = 0; r < 4; ++r) {
                const int row = row0 + wm + 16*i + (lane >> 4)*4 + r;
                float v = acc[i][j][r] + bv;
                if constexpr (RELU) v = fmaxf(v, 0.f);
                if constexpr (CM == 0) Cf[(size_t)row*DIMD + col] = v;
                else                   Cp[(size_t)row*DIMD + col] = split2_pack(v);
            }
        }
    }
}

// ============================================================================
// fp32 tiled GEMM -- fallback path only
// ============================================================================
template<bool TRANS_B>
__global__ __launch_bounds__(256) void gemm_f32(
    const float* __restrict__ A, const float* __restrict__ B, float* __restrict__ C)
{
    __shared__ float As[16][132];
    __shared__ float Bs[16][132];
    const int tid  = threadIdx.x;
    const int tx   = tid & 15;
    const int ty   = tid >> 4;
    const int row0 = blockIdx.y * 128;
    const int col0 = blockIdx.x * 128;

    float acc[8][8];
    #pragma unroll
    for (int i = 0; i < 8; ++i)
        #pragma unroll
        for (int j = 0; j < 8; ++j) acc[i][j] = 0.f;

    for (int k0 = 0; k0 < DIMD; k0 += 16) {
        #pragma unroll
        for (int t = 0; t < 2; ++t) {
            int i  = tid + t * 256;
            int arr = i >> 2, ak = (i & 3) << 2;
            float4 av = *(const float4*)(A + (size_t)(row0 + arr) * DIMD + k0 + ak);
            As[ak + 0][arr] = av.x; As[ak + 1][arr] = av.y;
            As[ak + 2][arr] = av.z; As[ak + 3][arr] = av.w;
            if constexpr (TRANS_B) {
                float4 bv4 = *(const float4*)(B + (size_t)(col0 + arr) * DIMD + k0 + ak);
                Bs[ak + 0][arr] = bv4.x; Bs[ak + 1][arr] = bv4.y;
                Bs[ak + 2][arr] = bv4.z; Bs[ak + 3][arr] = bv4.w;
            } else {
                int br = i >> 5, bc = (i & 31) << 2;
                *(float4*)&Bs[br][bc] =
                    *(const float4*)(B + (size_t)(k0 + br) * DIMD + col0 + bc);
            }
        }
        __syncthreads();
        #pragma unroll
        for (int kk = 0; kk < 16; ++kk) {
            float a[8], b[8];
            *(float4*)&a[0] = *(const float4*)&As[kk][ty * 8];
            *(float4*)&a[4] = *(const float4*)&As[kk][ty * 8 + 4];
            *(float4*)&b[0] = *(const float4*)&Bs[kk][tx * 4];
            *(float4*)&b[4] = *(const float4*)&Bs[kk][64 + tx * 4];
            #pragma unroll
            for (int i = 0; i < 8; ++i)
                #pragma unroll
                for (int j = 0; j < 8; ++j)
                    acc[i][j] = fmaf(a[i], b[j], acc[i][j]);
        }
        __syncthreads();
    }
    #pragma unroll
    for (int i = 0; i < 8; ++i) {
        size_t rr = (size_t)(row0 + ty * 8 + i) * DIMD;
        *(float4*)(C + rr + col0 + tx * 4)      = *(float4*)&acc[i][0];
        *(float4*)(C + rr + col0 + 64 + tx * 4) = *(float4*)&acc[i][4];
    }
}

// ============================================================================
// y[i] = W[i,:]·x ; W^T@x partials ; dot -- small-vector precomputes
// ============================================================================
__global__ __launch_bounds__(256) void mv_kernel(
    const float* __restrict__ W, const float* __restrict__ x,
    float* __restrict__ y)
{
    const int row  = blockIdx.x * 4 + (threadIdx.x >> 6);
    const int lane = threadIdx.x & 63;
    float a = 0.f;
    #pragma unroll
    for (int c = 0; c < 16; ++c) {
        int off = c * 64 + lane;
        a = fmaf(W[(size_t)row * DIMD + off], x[off], a);
    }
    #pragma unroll
    for (int d = 1; d < 64; d <<= 1) a += __shfl_xor(a, d);
    if (lane == 0) y[row] = a;
}

__global__ __launch_bounds__(1024) void mvt_part_kernel(
    const float* __restrict__ W, const float* __restrict__ x,
    float* __restrict__ part)
{
    const int b   = blockIdx.x;
    const int tid = threadIdx.x;
    float a = 0.f;
    #pragma unroll 4
    for (int j = b * 64; j < b * 64 + 64; ++j)
        a = fmaf(W[(size_t)j * DIMD + tid], x[j], a);
    part[(size_t)b * DIMD + tid] = a;
}
__global__ __launch_bounds__(256) void mvt_red_kernel(
    const float* __restrict__ part, float* __restrict__ y)
{
    const int i = blockIdx.x * 256 + threadIdx.x;
    float s = 0.f;
    #pragma unroll
    for (int c = 0; c < 16; ++c) s += part[(size_t)c * DIMD + i];
    y[i] = s;
}

__global__ __launch_bounds__(1024) void dot_kernel(
    const float* __restrict__ a, const float* __restrict__ b,
    float* __restrict__ out)
{
    __shared__ float red[16];
    const int tid = threadIdx.x;
    float p = a[tid] * b[tid];
    #pragma unroll
    for (int d = 1; d < 64; d <<= 1) p += __shfl_xor(p, d);
    if ((tid & 63) == 0) red[tid >> 6] = p;
    __syncthreads();
    if (tid < 16) {
        float x = red[tid];
        #pragma unroll
        for (int d = 1; d < 16; d <<= 1) x += __shfl_xor(x, d);
        if (tid == 0) out[0] = x;
    }
}

// ============================================================================
// plane splitters (full path)
// ============================================================================
// fp32 [m][k] -> hi/lo bf16 planes (A-side)
__global__ __launch_bounds__(256) void splitw2(
    const float* __restrict__ in, ushort_t* __restrict__ oh, ushort_t* __restrict__ ol)
{
    const size_t i = ((size_t)blockIdx.x * 256 + threadIdx.x) * 4;
    float4 v = *(const float4*)(in + i);
    uint_t p0 = split2_pack(v.x), p1 = split2_pack(v.y);
    uint_t p2 = split2_pack(v.z), p3 = split2_pack(v.w);
    uint2 h, l;
    h.x = (p0 & 0xFFFFu) | (p1 << 16);        h.y = (p2 & 0xFFFFu) | (p3 << 16);
    l.x = (p0 >> 16)     | (p1 & 0xFFFF0000u); l.y = (p2 >> 16)    | (p3 & 0xFFFF0000u);
    *(uint2*)(oh + i) = h;
    *(uint2*)(ol + i) = l;
}

// fp32 W[k][n] -> TRANSPOSED hi/lo planes Bt[n][k] (B-side), LDS-tiled
__global__ __launch_bounds__(256) void splitwt2(
    const float* __restrict__ in, ushort_t* __restrict__ oh, ushort_t* __restrict__ ol)
{
    __shared__ float tile[64][65];
    const int bx = blockIdx.x & 15;     // n-tile
    const int by = blockIdx.x >> 4;     // k-tile
    const int c  = threadIdx.x & 63;
    const int r4 = threadIdx.x >> 6;    // 0..3
    #pragma unroll
    for (int rr = 0; rr < 64; rr += 4)
        tile[rr + r4][c] = in[(size_t)(by * 64 + rr + r4) * DIMD + bx * 64 + c];
    __syncthreads();
    #pragma unroll
    for (int rr = 0; rr < 64; rr += 4) {
        uint_t p = split2_pack(tile[c][rr + r4]);
        size_t o = (size_t)(bx * 64 + rr + r4) * DIMD + by * 64 + c;
        oh[o] = (ushort_t)(p & 0xFFFFu);
        ol[o] = (ushort_t)(p >> 16);
    }
}

// x = text + pos -> hi/lo planes
__global__ __launch_bounds__(256) void splitx2(
    const float* __restrict__ text, const float* __restrict__ pos,
    ushort_t* __restrict__ oh, ushort_t* __restrict__ ol)
{
    const size_t i = ((size_t)blockIdx.x * 256 + threadIdx.x) * 4;
    float4 a = *(const float4*)(text + i);
    float4 b = *(const float4*)(pos + i);
    uint_t p0 = split2_pack(a.x + b.x), p1 = split2_pack(a.y + b.y);
    uint_t p2 = split2_pack(a.z + b.z), p3 = split2_pack(a.w + b.w);
    uint2 h, l;
    h.x = (p0 & 0xFFFFu) | (p1 << 16);        h.y = (p2 & 0xFFFFu) | (p3 << 16);
    l.x = (p0 >> 16)     | (p1 & 0xFFFF0000u); l.y = (p2 >> 16)    | (p3 & 0xFFFF0000u);
    *(uint2*)(oh + i) = h;
    *(uint2*)(ol + i) = l;
}

// x = text + pos -> packed (fallback)
__global__ __launch_bounds__(256) void splitx_kernel(
    const float* __restrict__ text, const float* __restrict__ pos,
    uint_t* __restrict__ out)
{
    const size_t i = ((size_t)blockIdx.x * 256 + threadIdx.x) * 4;
    float4 a = *(const float4*)(text + i);
    float4 b = *(const float4*)(pos + i);
    uint4 o;
    o.x = split2_pack(a.x + b.x); o.y = split2_pack(a.y + b.y);
    o.z = split2_pack(a.z + b.z); o.w = split2_pack(a.w + b.w);
    *(uint4*)(out + i) = o;
}

// ============================================================================
// attn1 phase 1 (plane readers, full path): scores + softmax -> prob
// ============================================================================
__global__ __launch_bounds__(256) void score2(
    const ushort_t* __restrict__ qh, const ushort_t* __restrict__ ql,
    const ushort_t* __restrict__ kh, const ushort_t* __restrict__ kl,
    float* __restrict__ prob)
{
    const int l    = blockIdx.x;
    const int qi   = threadIdx.x >> 6;
    const int lane = threadIdx.x & 63;
    const size_t base = (size_t)l * 4 * DIMD;
    const float scale = 0.125f;

    #pragma unroll 1
    for (int h = 0; h < 16; ++h) {
        int off = h * 64 + lane;
        float qv = up2(qh[base + qi * DIMD + off], ql[base + qi * DIMD + off]);
        float s0 = qv * up2(kh[base + 0 * DIMD + off], kl[base + 0 * DIMD + off]);
        float s1 = qv * up2(kh[base + 1 * DIMD + off], kl[base + 1 * DIMD + off]);
        float s2 = qv * up2(kh[base + 2 * DIMD + off], kl[base + 2 * DIMD + off]);
        float s3 = qv * up2(kh[base + 3 * DIMD + off], kl[base + 3 * DIMD + off]);
        #pragma unroll
        for (int d = 1; d < 64; d <<= 1) {
            s0 += __shfl_xor(s0, d);
            s1 += __shfl_xor(s1, d);
            s2 += __shfl_xor(s2, d);
            s3 += __shfl_xor(s3, d);
        }
        s0 *= scale; s1 *= scale; s2 *= scale; s3 *= scale;
        float mx = fmaxf(fmaxf(s0, s1), fmaxf(s2, s3));
        float e0 = expf(s0 - mx), e1 = expf(s1 - mx);
        float e2 = expf(s2 - mx), e3 = expf(s3 - mx);
        float inv = 1.f / (e0 + e1 + e2 + e3);
        if (lane == 0) {
            float4 p = { e0 * inv, e1 * inv, e2 * inv, e3 * inv };
            *(float4*)&prob[(((size_t)l * 4 + qi) * 16 + h) * 4] = p;
        }
    }
}

// fallback packed score
__global__ __launch_bounds__(256) void score_kernel(
    const uint_t* __restrict__ q, const uint_t* __restrict__ k,
    float* __restrict__ prob)
{
    const int l    = blockIdx.x;
    const int qi   = threadIdx.x >> 6;
    const int lane = threadIdx.x & 63;
    const size_t base = (size_t)l * 4 * DIMD;
    const float scale = 0.125f;

    #pragma unroll 1
    for (int h = 0; h < 16; ++h) {
        int off = h * 64 + lane;
        float qv = updp(q[base + qi * DIMD + off]);
        float s0 = qv * updp(k[base + 0 * DIMD + off]);
        float s1 = qv * updp(k[base + 1 * DIMD + off]);
        float s2 = qv * updp(k[base + 2 * DIMD + off]);
        float s3 = qv * updp(k[base + 3 * DIMD + off]);
        #pragma unroll
        for (int d = 1; d < 64; d <<= 1) {
            s0 += __shfl_xor(s0, d);
            s1 += __shfl_xor(s1, d);
            s2 += __shfl_xor(s2, d);
            s3 += __shfl_xor(s3, d);
        }
        s0 *= scale; s1 *= scale; s2 *= scale; s3 *= scale;
        float mx = fmaxf(fmaxf(s0, s1), fmaxf(s2, s3));
        float e0 = expf(s0 - mx), e1 = expf(s1 - mx);
        float e2 = expf(s2 - mx), e3 = expf(s3 - mx);
        float inv = 1.f / (e0 + e1 + e2 + e3);
        if (lane == 0) {
            float4 p = { e0 * inv, e1 * inv, e2 * inv, e3 * inv };
            *(float4*)&prob[(((size_t)l * 4 + qi) * 16 + h) * 4] = p;
        }
    }
}

// ============================================================================
// mix + LN fused (plane version, full path): y planes out, inter never in HBM
// ============================================================================
__global__ __launch_bounds__(256) void mixln2(
    const ushort_t* __restrict__ vh, const ushort_t* __restrict__ vl,
    const float* __restrict__ prob,
    const float* __restrict__ text, const float* __restrict__ pos,
    const float* __restrict__ g, const float* __restrict__ b,
    ushort_t* __restrict__ yh, ushort_t* __restrict__ yl)
{
    const int l    = blockIdx.x;
    const int qi   = threadIdx.x >> 6;
    const int lane = threadIdx.x & 63;
    const size_t base  = (size_t)l * 4 * DIMD;
    const size_t rbase = base + (size_t)qi * DIMD;
    float v[16];
    float s = 0.f;
    #pragma unroll
    for (int c = 0; c < 16; ++c) {
        int off = c * 64 + lane;
        float4 p = *(const float4*)&prob[(((size_t)l * 4 + qi) * 16 + c) * 4];
        float r = p.x * up2(vh[base + 0 * DIMD + off], vl[base + 0 * DIMD + off])
                + p.y * up2(vh[base + 1 * DIMD + off], vl[base + 1 * DIMD + off])
                + p.z * up2(vh[base + 2 * DIMD + off], vl[base + 2 * DIMD + off])
                + p.w * up2(vh[base + 3 * DIMD + off], vl[base + 3 * DIMD + off]);
        v[c] = r + text[rbase + off] + pos[rbase + off];
        s += v[c];
    }
    #pragma unroll
    for (int d = 1; d < 64; d <<= 1) s += __shfl_xor(s, d);
    float mu = s * (1.f / 1024.f);
    float vs = 0.f;
    #pragma unroll
    for (int c = 0; c < 16; ++c) { float t = v[c] - mu; vs += t * t; }
    #pragma unroll
    for (int d = 1; d < 64; d <<= 1) vs += __shfl_xor(vs, d);
    float rs = rsqrtf(vs * (1.f / 1024.f) + 1e-5f);
    #pragma unroll
    for (int c = 0; c < 16; ++c) {
        int off = c * 64 + lane;
        float y = (v[c] - mu) * rs * g[off] + b[off];
        uint_t p = split2_pack(y);
        yh[rbase + off] = (ushort_t)(p & 0xFFFFu);
        yl[rbase + off] = (ushort_t)(p >> 16);
    }
}

// fallback packed mixln
__global__ __launch_bounds__(256) void mixln_kernel(
    const uint_t* __restrict__ vmat, const float* __restrict__ prob,
    const float* __restrict__ text, const float* __restrict__ pos,
    const float* __restrict__ g, const float* __restrict__ b,
    uint_t* __restrict__ yp)
{
    const int l    = blockIdx.x;
    const int qi   = threadIdx.x >> 6;
    const int lane = threadIdx.x & 63;
    const size_t base  = (size_t)l * 4 * DIMD;
    const size_t rbase = base + (size_t)qi * DIMD;
    float v[16];
    float s = 0.f;
    #pragma unroll
    for (int c = 0; c < 16; ++c) {
        int off = c * 64 + lane;
        float4 p = *(const float4*)&prob[(((size_t)l * 4 + qi) * 16 + c) * 4];
        float r = p.x * updp(vmat[base + 0 * DIMD + off])
                + p.y * updp(vmat[base + 1 * DIMD + off])
                + p.z * updp(vmat[base + 2 * DIMD + off])
                + p.w * updp(vmat[base + 3 * DIMD + off]);
        v[c] = r + text[rbase + off] + pos[rbase + off];
        s += v[c];
    }
    #pragma unroll
    for (int d = 1; d < 64; d <<= 1) s += __shfl_xor(s, d);
    float mu = s * (1.f / 1024.f);
    float vs = 0.f;
    #pragma unroll
    for (int c = 0; c < 16; ++c) { float t = v[c] - mu; vs += t * t; }
    #pragma unroll
    for (int d = 1; d < 64; d <<= 1) vs += __shfl_xor(vs, d);
    float rs = rsqrtf(vs * (1.f / 1024.f) + 1e-5f);
    #pragma unroll
    for (int c = 0; c < 16; ++c) {
        int off = c * 64 + lane;
        float y = (v[c] - mu) * rs * g[off] + b[off];
        yp[rbase + off] = split2_pack(y);
    }
}

// ============================================================================
// Single-head attention + out_k + lstm preamble (plane version, full path)
// ============================================================================
__global__ __launch_bounds__(256) void attn2out2(
    const ushort_t* __restrict__ xh, const ushort_t* __restrict__ xl,
    const float* __restrict__ t,
    const float* __restrict__ wvec2, const float* __restrict__ czv,
    const float* __restrict__ prices,
    const float* __restrict__ Wih, const float* __restrict__ bih,
    const float* __restrict__ bhh,
    float* __restrict__ lstm_in, float* __restrict__ pre)
{
    const int l    = blockIdx.x;
    const int qi   = threadIdx.x >> 6;
    const int lane = threadIdx.x & 63;
    const size_t base = (size_t)l * 4 * DIMD;
    __shared__ float li[9];

    float s0 = 0.f, s1 = 0.f, s2 = 0.f, s3 = 0.f;
    float z0 = 0.f, z1 = 0.f, z2 = 0.f, z3 = 0.f;
    #pragma unroll
    for (int c = 0; c < 16; ++c) {
        int off = c * 64 + lane;
        float tv = t[base + qi * DIMD + off];
        float wv = wvec2[off];
        float x0 = up2(xh[base + 0 * DIMD + off], xl[base + 0 * DIMD + off]);
        float x1 = up2(xh[base + 1 * DIMD + off], xl[base + 1 * DIMD + off]);
        float x2 = up2(xh[base + 2 * DIMD + off], xl[base + 2 * DIMD + off]);
        float x3 = up2(xh[base + 3 * DIMD + off], xl[base + 3 * DIMD + off]);
        s0 = fmaf(tv, x0, s0); z0 = fmaf(wv, x0, z0);
        s1 = fmaf(tv, x1, s1); z1 = fmaf(wv, x1, z1);
        s2 = fmaf(tv, x2, s2); z2 = fmaf(wv, x2, z2);
        s3 = fmaf(tv, x3, s3); z3 = fmaf(wv, x3, z3);
    }
    #pragma unroll
    for (int d = 1; d < 64; d <<= 1) {
        s0 += __shfl_xor(s0, d); s1 += __shfl_xor(s1, d);
        s2 += __shfl_xor(s2, d); s3 += __shfl_xor(s3, d);
        z0 += __shfl_xor(z0, d); z1 += __shfl_xor(z1, d);
        z2 += __shfl_xor(z2, d); z3 += __shfl_xor(z3, d);
    }
    const float cz = czv[0];
    z0 += cz; z1 += cz; z2 += cz; z3 += cz;
    const float scale = 0.03125f;
    s0 *= scale; s1 *= scale; s2 *= scale; s3 *= scale;
    float mx = fmaxf(fmaxf(s0, s1), fmaxf(s2, s3));
    float e0 = expf(s0 - mx), e1 = expf(s1 - mx);
    float e2 = expf(s2 - mx), e3 = expf(s3 - mx);
    float inv = 1.f / (e0 + e1 + e2 + e3);
    float ok = (e0 * z0 + e1 * z1 + e2 * z2 + e3 * z3) * inv;

    if (lane == 0) li[qi] = ok;
    if (threadIdx.x >= 64 && threadIdx.x < 69)
        li[4 + threadIdx.x - 64] = prices[(size_t)l * 5 + threadIdx.x - 64];
    __syncthreads();
    if (threadIdx.x < 9) lstm_in[(size_t)l * 9 + threadIdx.x] = li[threadIdx.x];
    if (threadIdx.x < 20) {
        int gg = threadIdx.x;
        float p = bih[gg] + bhh[gg];
        #pragma unroll
        for (int j = 0; j < 9; ++j) p = fmaf(li[j], Wih[gg * 9 + j], p);
        pre[(size_t)l * 20 + (gg % 5) * 4 + (gg / 5)] = p;
    }
}

// fallback packed attn2out
__global__ __launch_bounds__(256) void attn2out_kernel(
    const uint_t* __restrict__ xp, const float* __restrict__ t,
    const float* __restrict__ wvec2, const float* __restrict__ czv,
    const float* __restrict__ prices,
    const float* __restrict__ Wih, const float* __restrict__ bih,
    const float* __restrict__ bhh,
    float* __restrict__ lstm_in, float* __restrict__ pre)
{
    const int l    = blockIdx.x;
    const int qi   = threadIdx.x >> 6;
    const int lane = threadIdx.x & 63;
    const size_t base = (size_t)l * 4 * DIMD;
    __shared__ float li[9];

    float s0 = 0.f, s1 = 0.f, s2 = 0.f, s3 = 0.f;
    float z0 = 0.f, z1 = 0.f, z2 = 0.f, z3 = 0.f;
    #pragma unroll
    for (int c = 0; c < 16; ++c) {
        int off = c * 64 + lane;
        float tv = t[base + qi * DIMD + off];
        float wv = wvec2[off];
        float x0 = updp(xp[base + 0 * DIMD + off]);
        float x1 = updp(xp[base + 1 * DIMD + off]);
        float x2 = updp(xp[base + 2 * DIMD + off]);
        float x3 = updp(xp[base + 3 * DIMD + off]);
        s0 = fmaf(tv, x0, s0); z0 = fmaf(wv, x0, z0);
        s1 = fmaf(tv, x1, s1); z1 = fmaf(wv, x1, z1);
        s2 = fmaf(tv, x2, s2); z2 = fmaf(wv, x2, z2);
        s3 = fmaf(tv, x3, s3); z3 = fmaf(wv, x3, z3);
    }
    #pragma unroll
    for (int d = 1; d < 64; d <<= 1) {
        s0 += __shfl_xor(s0, d); s1 += __shfl_xor(s1, d);
        s2 += __shfl_xor(s2, d); s3 += __shfl_xor(s3, d);
        z0 += __shfl_xor(z0, d); z1 += __shfl_xor(z1, d);
        z2 += __shfl_xor(z2, d); z3 += __shfl_xor(z3, d);
    }
    const float cz = czv[0];
    z0 += cz; z1 += cz; z2 += cz; z3 += cz;
    const float scale = 0.03125f;
    s0 *= scale; s1 *= scale; s2 *= scale; s3 *= scale;
    float mx = fmaxf(fmaxf(s0, s1), fmaxf(s2, s3));
    float e0 = expf(s0 - mx), e1 = expf(s1 - mx);
    float e2 = expf(s2 - mx), e3 = expf(s3 - mx);
    float inv = 1.f / (e0 + e1 + e2 + e3);
    float ok = (e0 * z0 + e1 * z1 + e2 * z2 + e3 * z3) * inv;

    if (lane == 0) li[qi] = ok;
    if (threadIdx.x >= 64 && threadIdx.x < 69)
        li[4 + threadIdx.x - 64] = prices[(size_t)l * 5 + threadIdx.x - 64];
    __syncthreads();
    if (threadIdx.x < 9) lstm_in[(size_t)l * 9 + threadIdx.x] = li[threadIdx.x];
    if (threadIdx.x < 20) {
        int gg = threadIdx.x;
        float p = bih[gg] + bhh[gg];
        #pragma unroll
        for (int j = 0; j < 9; ++j) p = fmaf(li[j], Wih[gg * 9 + j], p);
        pre[(size_t)l * 20 + (gg % 5) * 4 + (gg / 5)] = p;
    }
}

// ============================================================================
// att = softmax(w_u^T @ tanh(w_m)) -- one block, 1024 threads.
// ============================================================================
__global__ __launch_bounds__(1024) void att_kernel(
    const float* __restrict__ w_u, const float* __restrict__ w_m,
    float* __restrict__ att)
{
    __shared__ float tj[1024];
    __shared__ float red[16];
    const int tid = threadIdx.x;
    tj[tid] = tanhf(w_m[tid]);
    __syncthreads();
    float a = 0.f;
    #pragma unroll 8
    for (int j = 0; j < 1024; ++j)
        a = fmaf(w_u[(size_t)j * 1024 + tid], tj[j], a);
    float m = a;
    #pragma unroll
    for (int d = 1; d < 64; d <<= 1) m = fmaxf(m, __shfl_xor(m, d));
    if ((tid & 63) == 0) red[tid >> 6] = m;
    __syncthreads();
    if (tid < 16) {
        float x = red[tid];
        #pragma unroll
        for (int d = 1; d < 16; d <<= 1) x = fmaxf(x, __shfl_xor(x, d));
        red[tid] = x;
    }
    __syncthreads();
    float mx = red[0];
    float e = expf(a - mx);
    float s = e;
    #pragma unroll
    for (int d = 1; d < 64; d <<= 1) s += __shfl_xor(s, d);
    __syncthreads();
    if ((tid & 63) == 0) red[tid >> 6] = s;
    __syncthreads();
    if (tid < 16) {
        float x = red[tid];
        #pragma unroll
        for (int d = 1; d < 16; d <<= 1) x += __shfl_xor(x, d);
        red[tid] = x;
    }
    __syncthreads();
    att[tid] = e / red[0];
}

// ============================================================================
// Chunked-parallel LSTM (32 blocks x 256 steps, <=512-step warmup from zero)
// ============================================================================
#define LCHUNK 256
#define LWARM  512

__device__ __forceinline__ float bcast(float x, int srclane) {
    return __uint_as_float(__builtin_amdgcn_readlane(__float_as_uint(x), srclane));
}
__device__ __forceinline__ float fsig(float x) {
    return __builtin_amdgcn_rcpf(1.f + __expf(-x));
}
__device__ __forceinline__ float ftanh(float x) {
    float e = __expf(-2.f * x);
    return (1.f - e) * __builtin_amdgcn_rcpf(1.f + e);
}

__global__ __launch_bounds__(64) void lstm_kernel(
    const float* __restrict__ pre, const float* __restrict__ Whh,
    float* __restrict__ hs)
{
    const int lane = threadIdx.x;
    const int m    = (lane < 5) ? lane : 0;
    const int blk  = blockIdx.x;
    const int cbase  = blk * LCHUNK;
    const int base   = (cbase >= LWARM) ? cbase - LWARM : 0;
    const int skip   = cbase - base;
    const int nsteps = skip + LCHUNK;

    f32x2 wif[5], wgo[5];
    #pragma unroll
    for (int j = 0; j < 5; ++j) {
        wif[j] = (f32x2){ Whh[( 0 + m) * 5 + j], Whh[( 5 + m) * 5 + j] };
        wgo[j] = (f32x2){ Whh[(10 + m) * 5 + j], Whh[(15 + m) * 5 + j] };
    }
    float cm = 0.f, hm = 0.f;
    float s0 = 0.f, s1 = 0.f, s2 = 0.f, s3 = 0.f, s4 = 0.f;

    float4 buf[16];
    #pragma unroll
    for (int j = 0; j < 16; ++j)
        buf[j] = *(const float4*)(pre + (size_t)(base + j) * 20 + m * 4);

    #define LSTM_STEP(j, EMIT)                                                  \
        {                                                                       \
            float4 p = buf[j];                                                  \
            buf[j] = *(const float4*)(pre + (size_t)(base + l0 + 16 + (j)) * 20 + m * 4); \
            f32x2 S0 = { s0, s0 }, S1 = { s1, s1 }, S2 = { s2, s2 };            \
            f32x2 S3 = { s3, s3 }, S4 = { s4, s4 };                             \
            f32x2 gif = { p.x, p.y };                                           \
            f32x2 ggo = { p.z, p.w };                                           \
            f32x2 t1 = S0 * wif[0] + gif;                                       \
            f32x2 t2 = S1 * wif[1] + S2 * wif[2];                               \
            f32x2 t3 = S3 * wif[3] + S4 * wif[4];                               \
            gif = t1 + t2 + t3;                                                 \
            f32x2 u1 = S0 * wgo[0] + ggo;                                       \
            f32x2 u2 = S1 * wgo[1] + S2 * wgo[2];                               \
            f32x2 u3 = S3 * wgo[3] + S4 * wgo[4];                               \
            ggo = u1 + u2 + u3;                                                 \
            float si = fsig(gif.x);                                             \
            float sf = fsig(gif.y);                                             \
            float tg = ftanh(ggo.x);                                            \
            float so = fsig(ggo.y);                                             \
            cm = fmaf(sf, cm, si * tg);                                         \
            hm = so * ftanh(cm);                                                \
            if (EMIT) hs[(size_t)(base + l0 + (j)) * 5 + m] = hm;               \
            s0 = bcast(hm, 0); s1 = bcast(hm, 1); s2 = bcast(hm, 2);            \
            s3 = bcast(hm, 3); s4 = bcast(hm, 4);                               \
        }

    int l0 = 0;
    for (; l0 < skip; l0 += 16) {
        #pragma unroll
        for (int j = 0; j < 16; ++j) LSTM_STEP(j, false)
    }
    for (; l0 < nsteps; l0 += 16) {
        #pragma unroll
        for (int j = 0; j < 16; ++j) LSTM_STEP(j, true)
    }
    #undef LSTM_STEP
}

// ============================================================================
// final / auxiliary heads
// ============================================================================
__global__ __launch_bounds__(256) void final_kernel(
    const float* __restrict__ lstm_in, const float* __restrict__ hs,
    const float* __restrict__ Wt, const float* __restrict__ bt,
    const float* __restrict__ Wa, const float* __restrict__ ba,
    float* __restrict__ out)
{
    const int l = blockIdx.x * 256 + threadIdx.x;
    float f[14];
    #pragma unroll
    for (int j = 0; j < 9; ++j) f[j] = lstm_in[(size_t)l * 9 + j];
    #pragma unroll
    for (int j = 0; j < 5; ++j) f[9 + j] = hs[(size_t)l * 5 + j];
    #pragma unroll
    for (int c = 0; c < 2; ++c) {
        float a = bt[c], b = ba[c];
        #pragma unroll
        for (int j = 0; j < 14; ++j) {
            a = fmaf(f[j], Wt[j * 2 + c], a);
            b = fmaf(f[j], Wa[j * 2 + c], b);
        }
        out[(size_t)l * 2 + c]         = a;
        out[16384 + (size_t)l * 2 + c] = b;
    }
}

// ============================================================================
extern "C" void kernel_launch(void* const* d_in, const int* in_sizes, int n_in,
                              void* d_out, int out_size, void* d_ws, size_t ws_size,
                              hipStream_t stream)
{
    const float* text   = (const float*)d_in[0];
    const float* prices = (const float*)d_in[1];
    const float* pos    = (const float*)d_in[2];
    const float* Wq1    = (const float*)d_in[3];
    const float* Wk1    = (const float*)d_in[4];
    const float* Wv1    = (const float*)d_in[5];
    const float* Wo1    = (const float*)d_in[6];
    const float* ln_g   = (const float*)d_in[7];
    const float* ln_b   = (const float*)d_in[8];
    const float* W1     = (const float*)d_in[9];
    const float* b1     = (const float*)d_in[10];
    const float* W2     = (const float*)d_in[11];
    const float* b2     = (const float*)d_in[12];
    const float* Wq2    = (const float*)d_in[13];
    const float* Wk2    = (const float*)d_in[14];
    const float* Wv2    = (const float*)d_in[15];
    const float* Wo2    = (const float*)d_in[16];
    const float* w_u    = (const float*)d_in[17];
    const float* w_m    = (const float*)d_in[18];
    const float* Wih    = (const float*)d_in[19];
    const float* Whh    = (const float*)d_in[20];
    const float* bih    = (const float*)d_in[21];
    const float* bhh    = (const float*)d_in[22];
    const float* Wt     = (const float*)d_in[23];
    const float* bt     = (const float*)d_in[24];
    const float* Wa     = (const float*)d_in[25];
    const float* ba     = (const float*)d_in[26];

    float* ws = (float*)d_ws;
    const size_t BUF = (size_t)NROW * DIMD;         // 33,554,432 elems / buffer
    const size_t MW  = (size_t)DIMD * DIMD;         // 1,048,576
    float* A = ws;
    float* B = ws + BUF;
    float* C = ws + 2 * BUF;
    float* F0   = ws + 3 * BUF;                     // fp32 MW scratch
    float* F1   = F0 + MW;                          // fp32 MW scratch
    float* attL = F1 + MW;                          // legacy 1024 slot
    float* U    = attL + 1024;                      // union: prob | lstm area
    float* prob    = U;                             // LAG*4*16*4 = 2,097,152
    float* lstm_in = U;
    float* pre     = lstm_in + (size_t)LAG * 9;
    float* hs      = pre + ((size_t)LAG * 20 + 400);
    uint_t* Wpk    = (uint_t*)(U + 2097152);        // 8 x MW slots (plane pairs)
    float* out     = (float*)d_out;

    const size_t need_base = ((size_t)(3 * BUF) + 2 * MW + 1024 + 2097152) * 4;
    const size_t need_full = need_base + 8 * MW * 4;
    const bool full = ws_size >= need_full;

    uint_t* Ap = (uint_t*)A;
    uint_t* Bp = (uint_t*)B;
    uint_t* Cp = (uint_t*)C;

    // plane views of big buffers (full path): hi plane, then lo plane
    ushort_t* Axh = (ushort_t*)A;  ushort_t* Axl = Axh + BUF;
    ushort_t* Bxh = (ushort_t*)B;  ushort_t* Bxl = Bxh + BUF;
    ushort_t* Cxh = (ushort_t*)C;  ushort_t* Cxl = Cxh + BUF;

    // weight slots: each MW uints = hi plane (MW ushorts) + lo plane (MW ushorts)
    uint_t* S0 = Wpk + 0 * MW;  uint_t* S1 = Wpk + 1 * MW;
    uint_t* S2 = Wpk + 2 * MW;  uint_t* S3 = Wpk + 3 * MW;
    uint_t* S4 = Wpk + 4 * MW;  uint_t* S6 = Wpk + 6 * MW;
    uint_t* S7 = Wpk + 7 * MW;
#define PH(s) ((ushort_t*)(s))
#define PL(s) ((ushort_t*)(s) + MW)
    float* vecs = full ? (float*)(Wpk + 5 * MW) : (float*)Wpk;
    float* attS  = vecs;
    float* tmpS  = vecs + 1024;
    float* wvec  = vecs + 2048;
    float* wvec2 = vecs + 3072;
    float* w_a   = vecs + 4096;
    float* w_b   = vecs + 5120;
    float* vv    = vecs + 6144;
    float* czv   = vecs + 7168;
    float* partS = vecs + 8192;

    dim3 gbig(4, 128), gsml(4, 4), gblk8(512);      // gemm8 grids
    dim3 ggrid(8, 256), gblk(256);                  // fallback mgemm
    dim3 pgrid(8, 8);

    // --- small-vector precomputes ---
    att_kernel<<<1, 1024, 0, stream>>>(w_u, w_m, attS);
    mv_kernel<<<256, 256, 0, stream>>>(Wo2, attS, tmpS);           // Wo2 @ att
    mv_kernel<<<256, 256, 0, stream>>>(Wv2, tmpS, wvec);           // wvec = Wv2@Wo2@att
    mv_kernel<<<256, 256, 0, stream>>>(W2, wvec, wvec2);           // wvec2 = W2 @ wvec
    dot_kernel<<<1, 1024, 0, stream>>>(b2, wvec, czv);             // cz = b2 · wvec
    mvt_part_kernel<<<16, 1024, 0, stream>>>(Wq2, b2, partS);      // w_a = Wq2^T @ b2
    mvt_red_kernel<<<4, 256, 0, stream>>>(partS, w_a);
    mv_kernel<<<256, 256, 0, stream>>>(Wk2, w_a, w_b);             // w_b = Wk2 @ w_a
    mv_kernel<<<256, 256, 0, stream>>>(W2, w_b, vv);               // v = W2 @ w_b

    if (full) {
        splitx2<<<32768, 256, 0, stream>>>(text, pos, Axh, Axl);   // x planes

        // weight prep (all products via gemm8; B-side always transposed planes)
        splitw2 <<<1024, 256, 0, stream>>>(W2,  PH(S6), PL(S6));
        splitwt2<<<256, 256, 0, stream>>>(Wq2, PH(S7), PL(S7));
        gemm8<0,false,false><<<gsml, gblk8, 0, stream>>>(PH(S6), PL(S6), PH(S7), PL(S7),
                                                         nullptr, F0, nullptr, nullptr); // E = W2@Wq2
        splitwt2<<<256, 256, 0, stream>>>(Wk2, PH(S7), PL(S7));
        gemm8<0,false,false><<<gsml, gblk8, 0, stream>>>(PH(S6), PL(S6), PH(S7), PL(S7),
                                                         nullptr, F1, nullptr, nullptr); // F = W2@Wk2
        splitw2<<<1024, 256, 0, stream>>>(F0, PH(S6), PL(S6));     // E planes
        splitw2<<<1024, 256, 0, stream>>>(F1, PH(S7), PL(S7));     // F planes (Bt of F^T)
        gemm8<0,false,false><<<gsml, gblk8, 0, stream>>>(PH(S6), PL(S6), PH(S7), PL(S7),
                                                         nullptr, F0, nullptr, nullptr); // Wss = E@F^T
        splitwt2<<<256, 256, 0, stream>>>(F0, PH(S3), PL(S3));     // Wss^T planes
        splitw2 <<<1024, 256, 0, stream>>>(Wv1, PH(S6), PL(S6));
        splitwt2<<<256, 256, 0, stream>>>(Wo1, PH(S7), PL(S7));
        gemm8<0,false,false><<<gsml, gblk8, 0, stream>>>(PH(S6), PL(S6), PH(S7), PL(S7),
                                                         nullptr, F1, nullptr, nullptr); // Wvo1 = Wv1@Wo1
        splitwt2<<<256, 256, 0, stream>>>(F1, PH(S4), PL(S4));     // Wvo1^T planes
        splitwt2<<<256, 256, 0, stream>>>(Wq1, PH(S0), PL(S0));
        splitwt2<<<256, 256, 0, stream>>>(Wk1, PH(S1), PL(S1));
        splitwt2<<<256, 256, 0, stream>>>(W1,  PH(S2), PL(S2));

        // big pipeline (5 GEMMs on the 256^2 deep-pipelined kernel)
        gemm8<1,false,false><<<gbig, gblk8, 0, stream>>>(Axh, Axl, PH(S0), PL(S0),
                                                         nullptr, nullptr, Bxh, Bxl);   // q
        gemm8<1,false,false><<<gbig, gblk8, 0, stream>>>(Axh, Axl, PH(S1), PL(S1),
                                                         nullptr, nullptr, Cxh, Cxl);   // k
        score2<<<LAG, 256, 0, stream>>>(Bxh, Bxl, Cxh, Cxl, prob);
        gemm8<1,false,false><<<gbig, gblk8, 0, stream>>>(Axh, Axl, PH(S4), PL(S4),
                                                         nullptr, nullptr, Bxh, Bxl);   // vmat (q dead)
        mixln2<<<LAG, 256, 0, stream>>>(Bxh, Bxl, prob, text, pos, ln_g, ln_b,
                                        Cxh, Cxl);                                       // y (k dead)
        gemm8<1,true ,true ><<<gbig, gblk8, 0, stream>>>(Cxh, Cxl, PH(S2), PL(S2),
                                                         b1, nullptr, Bxh, Bxl);        // relu (vmat dead)
        gemm8<0,true ,false><<<gbig, gblk8, 0, stream>>>(Bxh, Bxl, PH(S3), PL(S3),
                                                         vv, A, nullptr, nullptr);      // tt = relu@Wss+v (x dead)
        attn2out2<<<LAG, 256, 0, stream>>>(Bxh, Bxl, A, wvec2, czv, prices,
                                           Wih, bih, bhh, lstm_in, pre);
    } else {
        splitx_kernel<<<32768, 256, 0, stream>>>(text, pos, Ap);
        gemm_f32<false><<<pgrid, gblk, 0, stream>>>(W2, Wq2, U);            // E
        gemm_f32<false><<<pgrid, gblk, 0, stream>>>(W2, Wk2, U + MW);       // F
        gemm_f32<true ><<<pgrid, gblk, 0, stream>>>(U, U + MW, F0);         // Wss
        gemm_f32<false><<<pgrid, gblk, 0, stream>>>(Wv1, Wo1, F1);          // Wvo1

        mgemm<0,1,false,false><<<ggrid, gblk, 0, stream>>>(Ap, Wq1, nullptr, nullptr, Bp);
        mgemm<0,1,false,false><<<ggrid, gblk, 0, stream>>>(Ap, Wk1, nullptr, nullptr, Cp);
        score_kernel<<<LAG, 256, 0, stream>>>(Bp, Cp, prob);
        mgemm<0,1,false,false><<<ggrid, gblk, 0, stream>>>(Ap, F1,  nullptr, nullptr, Bp);
        mixln_kernel<<<LAG, 256, 0, stream>>>(Bp, prob, text, pos, ln_g, ln_b, Cp);
        mgemm<0,1,true ,true ><<<ggrid, gblk, 0, stream>>>(Cp, W1,  b1, nullptr, Bp);
        mgemm<0,0,true ,false><<<ggrid, gblk, 0, stream>>>(Bp, F0,  vv, A, nullptr);
        attn2out_kernel<<<LAG, 256, 0, stream>>>(Bp, A, wvec2, czv, prices,
                                                 Wih, bih, bhh, lstm_in, pre);
    }

    lstm_kernel <<<32, 64, 0, stream>>>(pre, Whh, hs);
    final_kernel<<<32, 256, 0, stream>>>(lstm_in, hs, Wt, bt, Wa, ba, out);
}

// Round 7
// 2279.005 us; speedup vs baseline: 2.0730x; 2.0730x over previous
//
#include <hip/hip_runtime.h>
#include <hip/hip_bf16.h>
#include <math.h>

#define LAG   8192
#define NROW  32768        // LAG * 4 tweets
#define DIMD  1024

typedef __attribute__((ext_vector_type(8))) short  short8;   // 8 bf16 (4 VGPRs)
typedef __attribute__((ext_vector_type(4))) float  f32x4;    // mfma acc
typedef __attribute__((ext_vector_type(2))) float  f32x2;
typedef unsigned short ushort_t;
typedef unsigned int   uint_t;

// fp32 -> packed (bf16 hi | bf16 lo << 16), RNE both. f ~= hi + lo (err ~2^-18*f)
__device__ __forceinline__ uint_t split2_pack(float f) {
    unsigned u = __float_as_uint(f);
    unsigned r = u + 0x7FFFu + ((u >> 16) & 1u);
    unsigned h = r >> 16;
    float hf = __uint_as_float(h << 16);
    float lf = f - hf;
    unsigned u2 = __float_as_uint(lf);
    unsigned r2 = u2 + 0x7FFFu + ((u2 >> 16) & 1u);
    return h | (r2 & 0xFFFF0000u);
}
// packed -> fp32 value
__device__ __forceinline__ float updp(uint_t p) {
    return __uint_as_float(p << 16) + __uint_as_float(p & 0xFFFF0000u);
}
// separate planes -> fp32 value
__device__ __forceinline__ float up2(ushort_t h, ushort_t l) {
    return __uint_as_float((uint_t)h << 16) + __uint_as_float((uint_t)l << 16);
}

// async global->LDS, 16B per lane; LDS dest = wave-uniform base + lane*16 (HW)
__device__ __forceinline__ void gload16(const ushort_t* g, ushort_t* l) {
    __builtin_amdgcn_global_load_lds(
        (const __attribute__((address_space(1))) unsigned int*)(const void*)g,
        (__attribute__((address_space(3))) unsigned int*)(void*)l,
        16, 0, 0);
}

// unpack 16 packed uints -> hi-plane 16B x2 and lo-plane 16B x2 (fallback path)
__device__ __forceinline__ void unpack16(const uint_t* r, uint4& h0, uint4& h1,
                                         uint4& l0, uint4& l1) {
    h0.x = __builtin_amdgcn_perm(r[1],  r[0],  0x05040100u);
    h0.y = __builtin_amdgcn_perm(r[3],  r[2],  0x05040100u);
    h0.z = __builtin_amdgcn_perm(r[5],  r[4],  0x05040100u);
    h0.w = __builtin_amdgcn_perm(r[7],  r[6],  0x05040100u);
    h1.x = __builtin_amdgcn_perm(r[9],  r[8],  0x05040100u);
    h1.y = __builtin_amdgcn_perm(r[11], r[10], 0x05040100u);
    h1.z = __builtin_amdgcn_perm(r[13], r[12], 0x05040100u);
    h1.w = __builtin_amdgcn_perm(r[15], r[14], 0x05040100u);
    l0.x = __builtin_amdgcn_perm(r[1],  r[0],  0x07060302u);
    l0.y = __builtin_amdgcn_perm(r[3],  r[2],  0x07060302u);
    l0.z = __builtin_amdgcn_perm(r[5],  r[4],  0x07060302u);
    l0.w = __builtin_amdgcn_perm(r[7],  r[6],  0x07060302u);
    l1.x = __builtin_amdgcn_perm(r[9],  r[8],  0x07060302u);
    l1.y = __builtin_amdgcn_perm(r[11], r[10], 0x07060302u);
    l1.z = __builtin_amdgcn_perm(r[13], r[12], 0x07060302u);
    l1.w = __builtin_amdgcn_perm(r[15], r[14], 0x07060302u);
}

// ============================================================================
// gemm8: 256x256-tile deep-pipelined bf16x3 GEMM,  C[M,1024] = act(A@B + bias)
// Inputs: A as separate hi/lo bf16 planes [M][1024]; B as TRANSPOSED planes
// Bt[n][k] (hi/lo). Split product = single bf16 GEMM over K=3072 in 3 segments:
//   seg0 (Ah,Bh), seg1 (Ah,Bl), seg2 (Al,Bh)   -> hh + hl + lh ~ fp32 accuracy.
// 512 thr (8 waves, 2M x 4N), per-wave out 128x64 (8x4 16x16x32 mfma frags).
// LDS 128 KiB: 2 buf x 4 regions [128 rows][64 k] bf16, XOR-swizzled.
// Staging: global_load_lds width 16 (no staging VGPRs -> no scratch spill,
// which killed the reg-staged v1: 1.27 GB scratch writes/dispatch). LDS dest
// is linear (wave-uniform base + lane*16); the chunk^=(row&7) swizzle is
// applied on the SOURCE address (rule: linear dest + inv-swz source + swz read).
// Per tile t: vmcnt(8) (t+1's 8 loads stay in flight -- never drain to 0);
// barrier; 24 ds_read + 64 MFMA on buf[b]; lgkmcnt(0); barrier; issue 8 loads
// for t+2 -> buf[b]. Peeled last tile waits vmcnt(0).
// Grid must be (4, M/256); bijective XCD swizzle via gridDim.y.
// ============================================================================
#define NT8 48

template<int CM, bool BIAS, bool RELU>
__global__ __launch_bounds__(512, 2) void gemm8(
    const ushort_t* __restrict__ Ah, const ushort_t* __restrict__ Al,
    const ushort_t* __restrict__ Bth, const ushort_t* __restrict__ Btl,
    const float* __restrict__ bias,
    float* __restrict__ Cf, ushort_t* __restrict__ Ch, ushort_t* __restrict__ Cl)
{
    __shared__ ushort_t lds8[65536];    // 2 buf x 4 regions x 8192 ushorts = 128 KiB
    const int tid  = threadIdx.x;
    const int lane = tid & 63;
    const int wave = tid >> 6;
    const int wr   = wave >> 2;         // 0..1 (M)
    const int wc   = wave & 3;          // 0..3 (N)
    const int ln15 = lane & 15;
    const int g    = lane >> 4;

    const int lin  = blockIdx.y * 4 + blockIdx.x;
    const int cpx  = gridDim.y >> 1;    // nwg/8
    const int swz  = (lin & 7) * cpx + (lin >> 3);
    const int row0 = (swz >> 2) * 256;
    const int col0 = (swz & 3) * 256;

    // staging source coords: lane l covers physical chunk (l&7) of row
    // wave*8+(l>>3) in each 64-row half; source chunk = (l&7)^(l>>3) so that
    // physical chunk p holds logical chunk p^(row&7)  [row&7 == l>>3]
    const int srow_g = wave * 8 + (lane >> 3);            // row within 64-half
    const int sch_g  = (lane & 7) ^ (lane >> 3);          // source chunk
    // fragment swizzled chunk offsets for reads (rr&7 == ln15&7)
    const int fx0 = ((g)     ^ (ln15 & 7)) * 8;           // ksub 0
    const int fx1 = ((4 + g) ^ (ln15 & 7)) * 8;           // ksub 1

    f32x4 acc[8][4] = {};

#define G8_STAGE(bb, tt)                                                        \
    {                                                                           \
        const int seg_ = (tt) >> 4;                                             \
        const int ko_  = ((tt) & 15) * 64;                                      \
        const ushort_t* ap_ = (seg_ == 2) ? Al  : Ah;                           \
        const ushort_t* bp_ = (seg_ == 1) ? Btl : Bth;                          \
        ushort_t* lb_ = lds8 + (bb) * 32768 + wave * 512;                       \
        gload16(ap_ + (size_t)(row0 +       srow_g) * DIMD + ko_ + sch_g * 8, lb_ + 0*8192 + 0*4096); \
        gload16(ap_ + (size_t)(row0 +  64 + srow_g) * DIMD + ko_ + sch_g * 8, lb_ + 0*8192 + 1*4096); \
        gload16(ap_ + (size_t)(row0 + 128 + srow_g) * DIMD + ko_ + sch_g * 8, lb_ + 1*8192 + 0*4096); \
        gload16(ap_ + (size_t)(row0 + 192 + srow_g) * DIMD + ko_ + sch_g * 8, lb_ + 1*8192 + 1*4096); \
        gload16(bp_ + (size_t)(col0 +       srow_g) * DIMD + ko_ + sch_g * 8, lb_ + 2*8192 + 0*4096); \
        gload16(bp_ + (size_t)(col0 +  64 + srow_g) * DIMD + ko_ + sch_g * 8, lb_ + 2*8192 + 1*4096); \
        gload16(bp_ + (size_t)(col0 + 128 + srow_g) * DIMD + ko_ + sch_g * 8, lb_ + 3*8192 + 0*4096); \
        gload16(bp_ + (size_t)(col0 + 192 + srow_g) * DIMD + ko_ + sch_g * 8, lb_ + 3*8192 + 1*4096); \
    }

#define G8_COMPUTE(bb)                                                          \
    {                                                                           \
        const ushort_t* Lb = lds8 + (bb) * 32768;                               \
        short8 af[4][2], bf0[2][2], bf1[2][2];                                  \
        _Pragma("unroll")                                                       \
        for (int i = 0; i < 4; ++i) {                                           \
            int rr = (2 * i + wr) * 16 + ln15;                                  \
            af[i][0] = *(const short8*)&Lb[rr * 64 + fx0];                      \
            af[i][1] = *(const short8*)&Lb[rr * 64 + fx1];                      \
        }                                                                       \
        _Pragma("unroll")                                                       \
        for (int j = 0; j < 2; ++j) {                                           \
            int rr = (4 * j + wc) * 16 + ln15;                                  \
            bf0[j][0] = *(const short8*)&Lb[2 * 8192 + rr * 64 + fx0];          \
            bf0[j][1] = *(const short8*)&Lb[2 * 8192 + rr * 64 + fx1];          \
        }                                                                       \
        __builtin_amdgcn_s_setprio(1);                                          \
        _Pragma("unroll")                                                       \
        for (int i = 0; i < 4; ++i)                                             \
            _Pragma("unroll")                                                   \
            for (int j = 0; j < 2; ++j) {                                       \
                acc[i][j] = __builtin_amdgcn_mfma_f32_16x16x32_bf16(af[i][0], bf0[j][0], acc[i][j], 0, 0, 0); \
                acc[i][j] = __builtin_amdgcn_mfma_f32_16x16x32_bf16(af[i][1], bf0[j][1], acc[i][j], 0, 0, 0); \
            }                                                                   \
        __builtin_amdgcn_s_setprio(0);                                          \
        _Pragma("unroll")                                                       \
        for (int j = 0; j < 2; ++j) {                                           \
            int rr = (4 * j + wc) * 16 + ln15;                                  \
            bf1[j][0] = *(const short8*)&Lb[3 * 8192 + rr * 64 + fx0];          \
            bf1[j][1] = *(const short8*)&Lb[3 * 8192 + rr * 64 + fx1];          \
        }                                                                       \
        __builtin_amdgcn_s_setprio(1);                                          \
        _Pragma("unroll")                                                       \
        for (int i = 0; i < 4; ++i)                                             \
            _Pragma("unroll")                                                   \
            for (int j = 0; j < 2; ++j) {                                       \
                acc[i][2 + j] = __builtin_amdgcn_mfma_f32_16x16x32_bf16(af[i][0], bf1[j][0], acc[i][2 + j], 0, 0, 0); \
                acc[i][2 + j] = __builtin_amdgcn_mfma_f32_16x16x32_bf16(af[i][1], bf1[j][1], acc[i][2 + j], 0, 0, 0); \
            }                                                                   \
        __builtin_amdgcn_s_setprio(0);                                          \
        _Pragma("unroll")                                                       \
        for (int i = 0; i < 4; ++i) {                                           \
            int rr = (2 * i + wr) * 16 + ln15;                                  \
            af[i][0] = *(const short8*)&Lb[1 * 8192 + rr * 64 + fx0];           \
            af[i][1] = *(const short8*)&Lb[1 * 8192 + rr * 64 + fx1];           \
        }                                                                       \
        __builtin_amdgcn_s_setprio(1);                                          \
        _Pragma("unroll")                                                       \
        for (int i = 0; i < 4; ++i)                                             \
            _Pragma("unroll")                                                   \
            for (int j = 0; j < 2; ++j) {                                       \
                acc[4 + i][j] = __builtin_amdgcn_mfma_f32_16x16x32_bf16(af[i][0], bf0[j][0], acc[4 + i][j], 0, 0, 0); \
                acc[4 + i][j] = __builtin_amdgcn_mfma_f32_16x16x32_bf16(af[i][1], bf0[j][1], acc[4 + i][j], 0, 0, 0); \
            }                                                                   \
        _Pragma("unroll")                                                       \
        for (int i = 0; i < 4; ++i)                                             \
            _Pragma("unroll")                                                   \
            for (int j = 0; j < 2; ++j) {                                       \
                acc[4 + i][2 + j] = __builtin_amdgcn_mfma_f32_16x16x32_bf16(af[i][0], bf1[j][0], acc[4 + i][2 + j], 0, 0, 0); \
                acc[4 + i][2 + j] = __builtin_amdgcn_mfma_f32_16x16x32_bf16(af[i][1], bf1[j][1], acc[4 + i][2 + j], 0, 0, 0); \
            }                                                                   \
        __builtin_amdgcn_s_setprio(0);                                          \
    }

    // prologue: tiles 0 and 1 staged into buf0/buf1 (16 loads in flight)
    G8_STAGE(0, 0);
    G8_STAGE(1, 1);

    for (int t = 0; t < NT8 - 1; ++t) {
        const int b = t & 1;
        asm volatile("s_waitcnt vmcnt(8)" ::: "memory");   // tile t landed; t+1 in flight
        __builtin_amdgcn_sched_barrier(0);
        __builtin_amdgcn_s_barrier();
        __builtin_amdgcn_sched_barrier(0);
        G8_COMPUTE(b);
        asm volatile("s_waitcnt lgkmcnt(0)" ::: "memory"); // all ds_reads of buf[b] done
        __builtin_amdgcn_sched_barrier(0);
        __builtin_amdgcn_s_barrier();
        __builtin_amdgcn_sched_barrier(0);
        if (t + 2 < NT8) G8_STAGE(b, t + 2);               // overwrite buf[b]
    }
    // peeled last tile: no newer loads in flight -> must drain fully
    asm volatile("s_waitcnt vmcnt(0)" ::: "memory");
    __builtin_amdgcn_sched_barrier(0);
    __builtin_amdgcn_s_barrier();
    __builtin_amdgcn_sched_barrier(0);
    G8_COMPUTE((NT8 - 1) & 1);

#undef G8_STAGE
#undef G8_COMPUTE

    // epilogue: C/D layout col=lane&15, row=(lane>>4)*4+reg (m89-verified)
    #pragma unroll
    for (int J = 0; J < 4; ++J) {
        const int col = col0 + ((J >> 1) * 8 + (J & 1) * 4 + wc) * 16 + ln15;
        float bv = 0.f;
        if constexpr (BIAS) bv = bias[col];
        #pragma unroll
        for (int I = 0; I < 8; ++I) {
            const int srow = (I >> 2) * 8 + 2 * (I & 3) + wr;
            #pragma unroll
            for (int r = 0; r < 4; ++r) {
                const int row = row0 + srow * 16 + g * 4 + r;
                float v = acc[I][J][r] + bv;
                if constexpr (RELU) v = fmaxf(v, 0.f);
                if constexpr (CM == 0) {
                    Cf[(size_t)row * DIMD + col] = v;
                } else {
                    uint_t p = split2_pack(v);
                    Ch[(size_t)row * DIMD + col] = (ushort_t)(p & 0xFFFFu);
                    Cl[(size_t)row * DIMD + col] = (ushort_t)(p >> 16);
                }
            }
        }
    }
}

// ============================================================================
// OLD bf16x3 split MFMA GEMM (128x128) -- retained for small-workspace fallback
// ============================================================================
template<int BM, int CM, bool BIAS, bool RELU>
__global__ __launch_bounds__(256) void mgemm(
    const uint_t* __restrict__ Apk, const void* __restrict__ Bsrc,
    const float* __restrict__ bias,
    float* __restrict__ Cf, uint_t* __restrict__ Cp)
{
    __shared__ ushort_t As_h[128*40], As_l[128*40], Bs_h[128*40], Bs_l[128*40];
    const int tid  = threadIdx.x;
    const int lane = tid & 63;
    const int wave = tid >> 6;
    const int wm   = (wave & 1) * 64;
    const int wn   = (wave >> 1) * 64;
    const int ln15 = lane & 15;
    const int q8   = (lane >> 4) * 8;
    const int lin  = blockIdx.y * 8 + blockIdx.x;
    const int swz  = (lin & 7) * gridDim.y + (lin >> 3);
    const int row0 = (swz >> 3) * 128;
    const int col0 = (swz & 7) * 128;

    const int ar  = tid >> 1;
    const int ako = (tid & 1) << 4;
    const int bn  = tid & 127;
    const int bk  = (tid >> 7) << 4;

    f32x4 acc[4][4] = {};

    uint_t a_r[16] __attribute__((aligned(16)));
    uint_t b_r[16] __attribute__((aligned(16)));

    {
        const uint_t* Apt = Apk + (size_t)(row0 + ar) * DIMD + ako;
        *(uint4*)&a_r[0]  = *(const uint4*)(Apt + 0);
        *(uint4*)&a_r[4]  = *(const uint4*)(Apt + 4);
        *(uint4*)&a_r[8]  = *(const uint4*)(Apt + 8);
        *(uint4*)&a_r[12] = *(const uint4*)(Apt + 12);
        if constexpr (BM == 1) {
            const uint_t* Bpt = (const uint_t*)Bsrc + (size_t)bk * DIMD + col0 + bn;
            #pragma unroll
            for (int i = 0; i < 16; ++i) b_r[i] = Bpt[(size_t)i * DIMD];
        } else {
            const float* Bpt = (const float*)Bsrc + (size_t)bk * DIMD + col0 + bn;
            #pragma unroll
            for (int i = 0; i < 16; ++i) b_r[i] = split2_pack(Bpt[(size_t)i * DIMD]);
        }
    }

    for (int k0 = 0; k0 < DIMD; k0 += 32) {
        __syncthreads();
        {
            uint4 h0, h1, l0, l1;
            unpack16(a_r, h0, h1, l0, l1);
            *(uint4*)&As_h[ar*40 + ako]     = h0;
            *(uint4*)&As_h[ar*40 + ako + 8] = h1;
            *(uint4*)&As_l[ar*40 + ako]     = l0;
            *(uint4*)&As_l[ar*40 + ako + 8] = l1;
            unpack16(b_r, h0, h1, l0, l1);
            *(uint4*)&Bs_h[bn*40 + bk]      = h0;
            *(uint4*)&Bs_h[bn*40 + bk + 8]  = h1;
            *(uint4*)&Bs_l[bn*40 + bk]      = l0;
            *(uint4*)&Bs_l[bn*40 + bk + 8]  = l1;
        }
        __syncthreads();

        if (k0 + 32 < DIMD) {
            const int kn = k0 + 32;
            const uint_t* Apt = Apk + (size_t)(row0 + ar) * DIMD + kn + ako;
            *(uint4*)&a_r[0]  = *(const uint4*)(Apt + 0);
            *(uint4*)&a_r[4]  = *(const uint4*)(Apt + 4);
            *(uint4*)&a_r[8]  = *(const uint4*)(Apt + 8);
            *(uint4*)&a_r[12] = *(const uint4*)(Apt + 12);
            if constexpr (BM == 1) {
                const uint_t* Bpt = (const uint_t*)Bsrc + (size_t)(kn + bk) * DIMD + col0 + bn;
                #pragma unroll
                for (int i = 0; i < 16; ++i) b_r[i] = Bpt[(size_t)i * DIMD];
            } else {
                const float* Bpt = (const float*)Bsrc + (size_t)(kn + bk) * DIMD + col0 + bn;
                #pragma unroll
                for (int i = 0; i < 16; ++i) b_r[i] = split2_pack(Bpt[(size_t)i * DIMD]);
            }
        }

        short8 fah[4], fal[4];
        #pragma unroll
        for (int i = 0; i < 4; ++i) {
            fah[i] = *(const short8*)&As_h[(wm + 16*i + ln15)*40 + q8];
            fal[i] = *(const short8*)&As_l[(wm + 16*i + ln15)*40 + q8];
        }
        #pragma unroll
        for (int j = 0; j < 4; ++j) {
            short8 fbh = *(const short8*)&Bs_h[(wn + 16*j + ln15)*40 + q8];
            short8 fbl = *(const short8*)&Bs_l[(wn + 16*j + ln15)*40 + q8];
            #pragma unroll
            for (int i = 0; i < 4; ++i) {
                acc[i][j] = __builtin_amdgcn_mfma_f32_16x16x32_bf16(fal[i], fbh, acc[i][j], 0, 0, 0);
                acc[i][j] = __builtin_amdgcn_mfma_f32_16x16x32_bf16(fah[i], fbl, acc[i][j], 0, 0, 0);
                acc[i][j] = __builtin_amdgcn_mfma_f32_16x16x32_bf16(fah[i], fbh, acc[i][j], 0, 0, 0);
            }
        }
    }

    #pragma unroll
    for (int j = 0; j < 4; ++j) {
        const int col = col0 + wn + 16*j + ln15;
        float bv = 0.f;
        if constexpr (BIAS) bv = bias[col];
        #pragma unroll
        for (int i = 0; i < 4; ++i) {
            #pragma unroll
            for (int r = 0; r < 4; ++r) {
                const int row = row0 + wm + 16*i + (lane >> 4)*4 + r;
                float v = acc[i][j][r] + bv;
                if constexpr (RELU) v = fmaxf(v, 0.f);
                if constexpr (CM == 0) Cf[(size_t)row*DIMD + col] = v;
                else                   Cp[(size_t)row*DIMD + col] = split2_pack(v);
            }
        }
    }
}

// ============================================================================
// fp32 tiled GEMM -- fallback path only
// ============================================================================
template<bool TRANS_B>
__global__ __launch_bounds__(256) void gemm_f32(
    const float* __restrict__ A, const float* __restrict__ B, float* __restrict__ C)
{
    __shared__ float As[16][132];
    __shared__ float Bs[16][132];
    const int tid  = threadIdx.x;
    const int tx   = tid & 15;
    const int ty   = tid >> 4;
    const int row0 = blockIdx.y * 128;
    const int col0 = blockIdx.x * 128;

    float acc[8][8];
    #pragma unroll
    for (int i = 0; i < 8; ++i)
        #pragma unroll
        for (int j = 0; j < 8; ++j) acc[i][j] = 0.f;

    for (int k0 = 0; k0 < DIMD; k0 += 16) {
        #pragma unroll
        for (int t = 0; t < 2; ++t) {
            int i  = tid + t * 256;
            int arr = i >> 2, ak = (i & 3) << 2;
            float4 av = *(const float4*)(A + (size_t)(row0 + arr) * DIMD + k0 + ak);
            As[ak + 0][arr] = av.x; As[ak + 1][arr] = av.y;
            As[ak + 2][arr] = av.z; As[ak + 3][arr] = av.w;
            if constexpr (TRANS_B) {
                float4 bv4 = *(const float4*)(B + (size_t)(col0 + arr) * DIMD + k0 + ak);
                Bs[ak + 0][arr] = bv4.x; Bs[ak + 1][arr] = bv4.y;
                Bs[ak + 2][arr] = bv4.z; Bs[ak + 3][arr] = bv4.w;
            } else {
                int br = i >> 5, bc = (i & 31) << 2;
                *(float4*)&Bs[br][bc] =
                    *(const float4*)(B + (size_t)(k0 + br) * DIMD + col0 + bc);
            }
        }
        __syncthreads();
        #pragma unroll
        for (int kk = 0; kk < 16; ++kk) {
            float a[8], b[8];
            *(float4*)&a[0] = *(const float4*)&As[kk][ty * 8];
            *(float4*)&a[4] = *(const float4*)&As[kk][ty * 8 + 4];
            *(float4*)&b[0] = *(const float4*)&Bs[kk][tx * 4];
            *(float4*)&b[4] = *(const float4*)&Bs[kk][64 + tx * 4];
            #pragma unroll
            for (int i = 0; i < 8; ++i)
                #pragma unroll
                for (int j = 0; j < 8; ++j)
                    acc[i][j] = fmaf(a[i], b[j], acc[i][j]);
        }
        __syncthreads();
    }
    #pragma unroll
    for (int i = 0; i < 8; ++i) {
        size_t rr = (size_t)(row0 + ty * 8 + i) * DIMD;
        *(float4*)(C + rr + col0 + tx * 4)      = *(float4*)&acc[i][0];
        *(float4*)(C + rr + col0 + 64 + tx * 4) = *(float4*)&acc[i][4];
    }
}

// ============================================================================
// y[i] = W[i,:]·x ; W^T@x partials ; dot -- small-vector precomputes
// ============================================================================
__global__ __launch_bounds__(256) void mv_kernel(
    const float* __restrict__ W, const float* __restrict__ x,
    float* __restrict__ y)
{
    const int row  = blockIdx.x * 4 + (threadIdx.x >> 6);
    const int lane = threadIdx.x & 63;
    float a = 0.f;
    #pragma unroll
    for (int c = 0; c < 16; ++c) {
        int off = c * 64 + lane;
        a = fmaf(W[(size_t)row * DIMD + off], x[off], a);
    }
    #pragma unroll
    for (int d = 1; d < 64; d <<= 1) a += __shfl_xor(a, d);
    if (lane == 0) y[row] = a;
}

__global__ __launch_bounds__(1024) void mvt_part_kernel(
    const float* __restrict__ W, const float* __restrict__ x,
    float* __restrict__ part)
{
    const int b   = blockIdx.x;
    const int tid = threadIdx.x;
    float a = 0.f;
    #pragma unroll 4
    for (int j = b * 64; j < b * 64 + 64; ++j)
        a = fmaf(W[(size_t)j * DIMD + tid], x[j], a);
    part[(size_t)b * DIMD + tid] = a;
}
__global__ __launch_bounds__(256) void mvt_red_kernel(
    const float* __restrict__ part, float* __restrict__ y)
{
    const int i = blockIdx.x * 256 + threadIdx.x;
    float s = 0.f;
    #pragma unroll
    for (int c = 0; c < 16; ++c) s += part[(size_t)c * DIMD + i];
    y[i] = s;
}

__global__ __launch_bounds__(1024) void dot_kernel(
    const float* __restrict__ a, const float* __restrict__ b,
    float* __restrict__ out)
{
    __shared__ float red[16];
    const int tid = threadIdx.x;
    float p = a[tid] * b[tid];
    #pragma unroll
    for (int d = 1; d < 64; d <<= 1) p += __shfl_xor(p, d);
    if ((tid & 63) == 0) red[tid >> 6] = p;
    __syncthreads();
    if (tid < 16) {
        float x = red[tid];
        #pragma unroll
        for (int d = 1; d < 16; d <<= 1) x += __shfl_xor(x, d);
        if (tid == 0) out[0] = x;
    }
}

// ============================================================================
// plane splitters (full path)
// ============================================================================
// fp32 [m][k] -> hi/lo bf16 planes (A-side)
__global__ __launch_bounds__(256) void splitw2(
    const float* __restrict__ in, ushort_t* __restrict__ oh, ushort_t* __restrict__ ol)
{
    const size_t i = ((size_t)blockIdx.x * 256 + threadIdx.x) * 4;
    float4 v = *(const float4*)(in + i);
    uint_t p0 = split2_pack(v.x), p1 = split2_pack(v.y);
    uint_t p2 = split2_pack(v.z), p3 = split2_pack(v.w);
    uint2 h, l;
    h.x = (p0 & 0xFFFFu) | (p1 << 16);        h.y = (p2 & 0xFFFFu) | (p3 << 16);
    l.x = (p0 >> 16)     | (p1 & 0xFFFF0000u); l.y = (p2 >> 16)    | (p3 & 0xFFFF0000u);
    *(uint2*)(oh + i) = h;
    *(uint2*)(ol + i) = l;
}

// fp32 W[k][n] -> TRANSPOSED hi/lo planes Bt[n][k] (B-side), LDS-tiled
__global__ __launch_bounds__(256) void splitwt2(
    const float* __restrict__ in, ushort_t* __restrict__ oh, ushort_t* __restrict__ ol)
{
    __shared__ float tile[64][65];
    const int bx = blockIdx.x & 15;     // n-tile
    const int by = blockIdx.x >> 4;     // k-tile
    const int c  = threadIdx.x & 63;
    const int r4 = threadIdx.x >> 6;    // 0..3
    #pragma unroll
    for (int rr = 0; rr < 64; rr += 4)
        tile[rr + r4][c] = in[(size_t)(by * 64 + rr + r4) * DIMD + bx * 64 + c];
    __syncthreads();
    #pragma unroll
    for (int rr = 0; rr < 64; rr += 4) {
        uint_t p = split2_pack(tile[c][rr + r4]);
        size_t o = (size_t)(bx * 64 + rr + r4) * DIMD + by * 64 + c;
        oh[o] = (ushort_t)(p & 0xFFFFu);
        ol[o] = (ushort_t)(p >> 16);
    }
}

// x = text + pos -> hi/lo planes
__global__ __launch_bounds__(256) void splitx2(
    const float* __restrict__ text, const float* __restrict__ pos,
    ushort_t* __restrict__ oh, ushort_t* __restrict__ ol)
{
    const size_t i = ((size_t)blockIdx.x * 256 + threadIdx.x) * 4;
    float4 a = *(const float4*)(text + i);
    float4 b = *(const float4*)(pos + i);
    uint_t p0 = split2_pack(a.x + b.x), p1 = split2_pack(a.y + b.y);
    uint_t p2 = split2_pack(a.z + b.z), p3 = split2_pack(a.w + b.w);
    uint2 h, l;
    h.x = (p0 & 0xFFFFu) | (p1 << 16);        h.y = (p2 & 0xFFFFu) | (p3 << 16);
    l.x = (p0 >> 16)     | (p1 & 0xFFFF0000u); l.y = (p2 >> 16)    | (p3 & 0xFFFF0000u);
    *(uint2*)(oh + i) = h;
    *(uint2*)(ol + i) = l;
}

// x = text + pos -> packed (fallback)
__global__ __launch_bounds__(256) void splitx_kernel(
    const float* __restrict__ text, const float* __restrict__ pos,
    uint_t* __restrict__ out)
{
    const size_t i = ((size_t)blockIdx.x * 256 + threadIdx.x) * 4;
    float4 a = *(const float4*)(text + i);
    float4 b = *(const float4*)(pos + i);
    uint4 o;
    o.x = split2_pack(a.x + b.x); o.y = split2_pack(a.y + b.y);
    o.z = split2_pack(a.z + b.z); o.w = split2_pack(a.w + b.w);
    *(uint4*)(out + i) = o;
}

// ============================================================================
// attn1 phase 1 (plane readers, full path): scores + softmax -> prob
// ============================================================================
__global__ __launch_bounds__(256) void score2(
    const ushort_t* __restrict__ qh, const ushort_t* __restrict__ ql,
    const ushort_t* __restrict__ kh, const ushort_t* __restrict__ kl,
    float* __restrict__ prob)
{
    const int l    = blockIdx.x;
    const int qi   = threadIdx.x >> 6;
    const int lane = threadIdx.x & 63;
    const size_t base = (size_t)l * 4 * DIMD;
    const float scale = 0.125f;

    #pragma unroll 1
    for (int h = 0; h < 16; ++h) {
        int off = h * 64 + lane;
        float qv = up2(qh[base + qi * DIMD + off], ql[base + qi * DIMD + off]);
        float s0 = qv * up2(kh[base + 0 * DIMD + off], kl[base + 0 * DIMD + off]);
        float s1 = qv * up2(kh[base + 1 * DIMD + off], kl[base + 1 * DIMD + off]);
        float s2 = qv * up2(kh[base + 2 * DIMD + off], kl[base + 2 * DIMD + off]);
        float s3 = qv * up2(kh[base + 3 * DIMD + off], kl[base + 3 * DIMD + off]);
        #pragma unroll
        for (int d = 1; d < 64; d <<= 1) {
            s0 += __shfl_xor(s0, d);
            s1 += __shfl_xor(s1, d);
            s2 += __shfl_xor(s2, d);
            s3 += __shfl_xor(s3, d);
        }
        s0 *= scale; s1 *= scale; s2 *= scale; s3 *= scale;
        float mx = fmaxf(fmaxf(s0, s1), fmaxf(s2, s3));
        float e0 = expf(s0 - mx), e1 = expf(s1 - mx);
        float e2 = expf(s2 - mx), e3 = expf(s3 - mx);
        float inv = 1.f / (e0 + e1 + e2 + e3);
        if (lane == 0) {
            float4 p = { e0 * inv, e1 * inv, e2 * inv, e3 * inv };
            *(float4*)&prob[(((size_t)l * 4 + qi) * 16 + h) * 4] = p;
        }
    }
}

// fallback packed score
__global__ __launch_bounds__(256) void score_kernel(
    const uint_t* __restrict__ q, const uint_t* __restrict__ k,
    float* __restrict__ prob)
{
    const int l    = blockIdx.x;
    const int qi   = threadIdx.x >> 6;
    const int lane = threadIdx.x & 63;
    const size_t base = (size_t)l * 4 * DIMD;
    const float scale = 0.125f;

    #pragma unroll 1
    for (int h = 0; h < 16; ++h) {
        int off = h * 64 + lane;
        float qv = updp(q[base + qi * DIMD + off]);
        float s0 = qv * updp(k[base + 0 * DIMD + off]);
        float s1 = qv * updp(k[base + 1 * DIMD + off]);
        float s2 = qv * updp(k[base + 2 * DIMD + off]);
        float s3 = qv * updp(k[base + 3 * DIMD + off]);
        #pragma unroll
        for (int d = 1; d < 64; d <<= 1) {
            s0 += __shfl_xor(s0, d);
            s1 += __shfl_xor(s1, d);
            s2 += __shfl_xor(s2, d);
            s3 += __shfl_xor(s3, d);
        }
        s0 *= scale; s1 *= scale; s2 *= scale; s3 *= scale;
        float mx = fmaxf(fmaxf(s0, s1), fmaxf(s2, s3));
        float e0 = expf(s0 - mx), e1 = expf(s1 - mx);
        float e2 = expf(s2 - mx), e3 = expf(s3 - mx);
        float inv = 1.f / (e0 + e1 + e2 + e3);
        if (lane == 0) {
            float4 p = { e0 * inv, e1 * inv, e2 * inv, e3 * inv };
            *(float4*)&prob[(((size_t)l * 4 + qi) * 16 + h) * 4] = p;
        }
    }
}

// ============================================================================
// mix + LN fused (plane version, full path): y planes out, inter never in HBM
// ============================================================================
__global__ __launch_bounds__(256) void mixln2(
    const ushort_t* __restrict__ vh, const ushort_t* __restrict__ vl,
    const float* __restrict__ prob,
    const float* __restrict__ text, const float* __restrict__ pos,
    const float* __restrict__ g, const float* __restrict__ b,
    ushort_t* __restrict__ yh, ushort_t* __restrict__ yl)
{
    const int l    = blockIdx.x;
    const int qi   = threadIdx.x >> 6;
    const int lane = threadIdx.x & 63;
    const size_t base  = (size_t)l * 4 * DIMD;
    const size_t rbase = base + (size_t)qi * DIMD;
    float v[16];
    float s = 0.f;
    #pragma unroll
    for (int c = 0; c < 16; ++c) {
        int off = c * 64 + lane;
        float4 p = *(const float4*)&prob[(((size_t)l * 4 + qi) * 16 + c) * 4];
        float r = p.x * up2(vh[base + 0 * DIMD + off], vl[base + 0 * DIMD + off])
                + p.y * up2(vh[base + 1 * DIMD + off], vl[base + 1 * DIMD + off])
                + p.z * up2(vh[base + 2 * DIMD + off], vl[base + 2 * DIMD + off])
                + p.w * up2(vh[base + 3 * DIMD + off], vl[base + 3 * DIMD + off]);
        v[c] = r + text[rbase + off] + pos[rbase + off];
        s += v[c];
    }
    #pragma unroll
    for (int d = 1; d < 64; d <<= 1) s += __shfl_xor(s, d);
    float mu = s * (1.f / 1024.f);
    float vs = 0.f;
    #pragma unroll
    for (int c = 0; c < 16; ++c) { float t = v[c] - mu; vs += t * t; }
    #pragma unroll
    for (int d = 1; d < 64; d <<= 1) vs += __shfl_xor(vs, d);
    float rs = rsqrtf(vs * (1.f / 1024.f) + 1e-5f);
    #pragma unroll
    for (int c = 0; c < 16; ++c) {
        int off = c * 64 + lane;
        float y = (v[c] - mu) * rs * g[off] + b[off];
        uint_t p = split2_pack(y);
        yh[rbase + off] = (ushort_t)(p & 0xFFFFu);
        yl[rbase + off] = (ushort_t)(p >> 16);
    }
}

// fallback packed mixln
__global__ __launch_bounds__(256) void mixln_kernel(
    const uint_t* __restrict__ vmat, const float* __restrict__ prob,
    const float* __restrict__ text, const float* __restrict__ pos,
    const float* __restrict__ g, const float* __restrict__ b,
    uint_t* __restrict__ yp)
{
    const int l    = blockIdx.x;
    const int qi   = threadIdx.x >> 6;
    const int lane = threadIdx.x & 63;
    const size_t base  = (size_t)l * 4 * DIMD;
    const size_t rbase = base + (size_t)qi * DIMD;
    float v[16];
    float s = 0.f;
    #pragma unroll
    for (int c = 0; c < 16; ++c) {
        int off = c * 64 + lane;
        float4 p = *(const float4*)&prob[(((size_t)l * 4 + qi) * 16 + c) * 4];
        float r = p.x * updp(vmat[base + 0 * DIMD + off])
                + p.y * updp(vmat[base + 1 * DIMD + off])
                + p.z * updp(vmat[base + 2 * DIMD + off])
                + p.w * updp(vmat[base + 3 * DIMD + off]);
        v[c] = r + text[rbase + off] + pos[rbase + off];
        s += v[c];
    }
    #pragma unroll
    for (int d = 1; d < 64; d <<= 1) s += __shfl_xor(s, d);
    float mu = s * (1.f / 1024.f);
    float vs = 0.f;
    #pragma unroll
    for (int c = 0; c < 16; ++c) { float t = v[c] - mu; vs += t * t; }
    #pragma unroll
    for (int d = 1; d < 64; d <<= 1) vs += __shfl_xor(vs, d);
    float rs = rsqrtf(vs * (1.f / 1024.f) + 1e-5f);
    #pragma unroll
    for (int c = 0; c < 16; ++c) {
        int off = c * 64 + lane;
        float y = (v[c] - mu) * rs * g[off] + b[off];
        yp[rbase + off] = split2_pack(y);
    }
}

// ============================================================================
// Single-head attention + out_k + lstm preamble (plane version, full path)
// ============================================================================
__global__ __launch_bounds__(256) void attn2out2(
    const ushort_t* __restrict__ xh, const ushort_t* __restrict__ xl,
    const float* __restrict__ t,
    const float* __restrict__ wvec2, const float* __restrict__ czv,
    const float* __restrict__ prices,
    const float* __restrict__ Wih, const float* __restrict__ bih,
    const float* __restrict__ bhh,
    float* __restrict__ lstm_in, float* __restrict__ pre)
{
    const int l    = blockIdx.x;
    const int qi   = threadIdx.x >> 6;
    const int lane = threadIdx.x & 63;
    const size_t base = (size_t)l * 4 * DIMD;
    __shared__ float li[9];

    float s0 = 0.f, s1 = 0.f, s2 = 0.f, s3 = 0.f;
    float z0 = 0.f, z1 = 0.f, z2 = 0.f, z3 = 0.f;
    #pragma unroll
    for (int c = 0; c < 16; ++c) {
        int off = c * 64 + lane;
        float tv = t[base + qi * DIMD + off];
        float wv = wvec2[off];
        float x0 = up2(xh[base + 0 * DIMD + off], xl[base + 0 * DIMD + off]);
        float x1 = up2(xh[base + 1 * DIMD + off], xl[base + 1 * DIMD + off]);
        float x2 = up2(xh[base + 2 * DIMD + off], xl[base + 2 * DIMD + off]);
        float x3 = up2(xh[base + 3 * DIMD + off], xl[base + 3 * DIMD + off]);
        s0 = fmaf(tv, x0, s0); z0 = fmaf(wv, x0, z0);
        s1 = fmaf(tv, x1, s1); z1 = fmaf(wv, x1, z1);
        s2 = fmaf(tv, x2, s2); z2 = fmaf(wv, x2, z2);
        s3 = fmaf(tv, x3, s3); z3 = fmaf(wv, x3, z3);
    }
    #pragma unroll
    for (int d = 1; d < 64; d <<= 1) {
        s0 += __shfl_xor(s0, d); s1 += __shfl_xor(s1, d);
        s2 += __shfl_xor(s2, d); s3 += __shfl_xor(s3, d);
        z0 += __shfl_xor(z0, d); z1 += __shfl_xor(z1, d);
        z2 += __shfl_xor(z2, d); z3 += __shfl_xor(z3, d);
    }
    const float cz = czv[0];
    z0 += cz; z1 += cz; z2 += cz; z3 += cz;
    const float scale = 0.03125f;
    s0 *= scale; s1 *= scale; s2 *= scale; s3 *= scale;
    float mx = fmaxf(fmaxf(s0, s1), fmaxf(s2, s3));
    float e0 = expf(s0 - mx), e1 = expf(s1 - mx);
    float e2 = expf(s2 - mx), e3 = expf(s3 - mx);
    float inv = 1.f / (e0 + e1 + e2 + e3);
    float ok = (e0 * z0 + e1 * z1 + e2 * z2 + e3 * z3) * inv;

    if (lane == 0) li[qi] = ok;
    if (threadIdx.x >= 64 && threadIdx.x < 69)
        li[4 + threadIdx.x - 64] = prices[(size_t)l * 5 + threadIdx.x - 64];
    __syncthreads();
    if (threadIdx.x < 9) lstm_in[(size_t)l * 9 + threadIdx.x] = li[threadIdx.x];
    if (threadIdx.x < 20) {
        int gg = threadIdx.x;
        float p = bih[gg] + bhh[gg];
        #pragma unroll
        for (int j = 0; j < 9; ++j) p = fmaf(li[j], Wih[gg * 9 + j], p);
        pre[(size_t)l * 20 + (gg % 5) * 4 + (gg / 5)] = p;
    }
}

// fallback packed attn2out
__global__ __launch_bounds__(256) void attn2out_kernel(
    const uint_t* __restrict__ xp, const float* __restrict__ t,
    const float* __restrict__ wvec2, const float* __restrict__ czv,
    const float* __restrict__ prices,
    const float* __restrict__ Wih, const float* __restrict__ bih,
    const float* __restrict__ bhh,
    float* __restrict__ lstm_in, float* __restrict__ pre)
{
    const int l    = blockIdx.x;
    const int qi   = threadIdx.x >> 6;
    const int lane = threadIdx.x & 63;
    const size_t base = (size_t)l * 4 * DIMD;
    __shared__ float li[9];

    float s0 = 0.f, s1 = 0.f, s2 = 0.f, s3 = 0.f;
    float z0 = 0.f, z1 = 0.f, z2 = 0.f, z3 = 0.f;
    #pragma unroll
    for (int c = 0; c < 16; ++c) {
        int off = c * 64 + lane;
        float tv = t[base + qi * DIMD + off];
        float wv = wvec2[off];
        float x0 = updp(xp[base + 0 * DIMD + off]);
        float x1 = updp(xp[base + 1 * DIMD + off]);
        float x2 = updp(xp[base + 2 * DIMD + off]);
        float x3 = updp(xp[base + 3 * DIMD + off]);
        s0 = fmaf(tv, x0, s0); z0 = fmaf(wv, x0, z0);
        s1 = fmaf(tv, x1, s1); z1 = fmaf(wv, x1, z1);
        s2 = fmaf(tv, x2, s2); z2 = fmaf(wv, x2, z2);
        s3 = fmaf(tv, x3, s3); z3 = fmaf(wv, x3, z3);
    }
    #pragma unroll
    for (int d = 1; d < 64; d <<= 1) {
        s0 += __shfl_xor(s0, d); s1 += __shfl_xor(s1, d);
        s2 += __shfl_xor(s2, d); s3 += __shfl_xor(s3, d);
        z0 += __shfl_xor(z0, d); z1 += __shfl_xor(z1, d);
        z2 += __shfl_xor(z2, d); z3 += __shfl_xor(z3, d);
    }
    const float cz = czv[0];
    z0 += cz; z1 += cz; z2 += cz; z3 += cz;
    const float scale = 0.03125f;
    s0 *= scale; s1 *= scale; s2 *= scale; s3 *= scale;
    float mx = fmaxf(fmaxf(s0, s1), fmaxf(s2, s3));
    float e0 = expf(s0 - mx), e1 = expf(s1 - mx);
    float e2 = expf(s2 - mx), e3 = expf(s3 - mx);
    float inv = 1.f / (e0 + e1 + e2 + e3);
    float ok = (e0 * z0 + e1 * z1 + e2 * z2 + e3 * z3) * inv;

    if (lane == 0) li[qi] = ok;
    if (threadIdx.x >= 64 && threadIdx.x < 69)
        li[4 + threadIdx.x - 64] = prices[(size_t)l * 5 + threadIdx.x - 64];
    __syncthreads();
    if (threadIdx.x < 9) lstm_in[(size_t)l * 9 + threadIdx.x] = li[threadIdx.x];
    if (threadIdx.x < 20) {
        int gg = threadIdx.x;
        float p = bih[gg] + bhh[gg];
        #pragma unroll
        for (int j = 0; j < 9; ++j) p = fmaf(li[j], Wih[gg * 9 + j], p);
        pre[(size_t)l * 20 + (gg % 5) * 4 + (gg / 5)] = p;
    }
}

// ============================================================================
// att = softmax(w_u^T @ tanh(w_m)) -- one block, 1024 threads.
// ============================================================================
__global__ __launch_bounds__(1024) void att_kernel(
    const float* __restrict__ w_u, const float* __restrict__ w_m,
    float* __restrict__ att)
{
    __shared__ float tj[1024];
    __shared__ float red[16];
    const int tid = threadIdx.x;
    tj[tid] = tanhf(w_m[tid]);
    __syncthreads();
    float a = 0.f;
    #pragma unroll 8
    for (int j = 0; j < 1024; ++j)
        a = fmaf(w_u[(size_t)j * 1024 + tid], tj[j], a);
    float m = a;
    #pragma unroll
    for (int d = 1; d < 64; d <<= 1) m = fmaxf(m, __shfl_xor(m, d));
    if ((tid & 63) == 0) red[tid >> 6] = m;
    __syncthreads();
    if (tid < 16) {
        float x = red[tid];
        #pragma unroll
        for (int d = 1; d < 16; d <<= 1) x = fmaxf(x, __shfl_xor(x, d));
        red[tid] = x;
    }
    __syncthreads();
    float mx = red[0];
    float e = expf(a - mx);
    float s = e;
    #pragma unroll
    for (int d = 1; d < 64; d <<= 1) s += __shfl_xor(s, d);
    __syncthreads();
    if ((tid & 63) == 0) red[tid >> 6] = s;
    __syncthreads();
    if (tid < 16) {
        float x = red[tid];
        #pragma unroll
        for (int d = 1; d < 16; d <<= 1) x += __shfl_xor(x, d);
        red[tid] = x;
    }
    __syncthreads();
    att[tid] = e / red[0];
}

// ============================================================================
// Chunked-parallel LSTM (32 blocks x 256 steps, <=512-step warmup from zero)
// ============================================================================
#define LCHUNK 256
#define LWARM  512

__device__ __forceinline__ float bcast(float x, int srclane) {
    return __uint_as_float(__builtin_amdgcn_readlane(__float_as_uint(x), srclane));
}
__device__ __forceinline__ float fsig(float x) {
    return __builtin_amdgcn_rcpf(1.f + __expf(-x));
}
__device__ __forceinline__ float ftanh(float x) {
    float e = __expf(-2.f * x);
    return (1.f - e) * __builtin_amdgcn_rcpf(1.f + e);
}

__global__ __launch_bounds__(64) void lstm_kernel(
    const float* __restrict__ pre, const float* __restrict__ Whh,
    float* __restrict__ hs)
{
    const int lane = threadIdx.x;
    const int m    = (lane < 5) ? lane : 0;
    const int blk  = blockIdx.x;
    const int cbase  = blk * LCHUNK;
    const int base   = (cbase >= LWARM) ? cbase - LWARM : 0;
    const int skip   = cbase - base;
    const int nsteps = skip + LCHUNK;

    f32x2 wif[5], wgo[5];
    #pragma unroll
    for (int j = 0; j < 5; ++j) {
        wif[j] = (f32x2){ Whh[( 0 + m) * 5 + j], Whh[( 5 + m) * 5 + j] };
        wgo[j] = (f32x2){ Whh[(10 + m) * 5 + j], Whh[(15 + m) * 5 + j] };
    }
    float cm = 0.f, hm = 0.f;
    float s0 = 0.f, s1 = 0.f, s2 = 0.f, s3 = 0.f, s4 = 0.f;

    float4 buf[16];
    #pragma unroll
    for (int j = 0; j < 16; ++j)
        buf[j] = *(const float4*)(pre + (size_t)(base + j) * 20 + m * 4);

    #define LSTM_STEP(j, EMIT)                                                  \
        {                                                                       \
            float4 p = buf[j];                                                  \
            buf[j] = *(const float4*)(pre + (size_t)(base + l0 + 16 + (j)) * 20 + m * 4); \
            f32x2 S0 = { s0, s0 }, S1 = { s1, s1 }, S2 = { s2, s2 };            \
            f32x2 S3 = { s3, s3 }, S4 = { s4, s4 };                             \
            f32x2 gif = { p.x, p.y };                                           \
            f32x2 ggo = { p.z, p.w };                                           \
            f32x2 t1 = S0 * wif[0] + gif;                                       \
            f32x2 t2 = S1 * wif[1] + S2 * wif[2];                               \
            f32x2 t3 = S3 * wif[3] + S4 * wif[4];                               \
            gif = t1 + t2 + t3;                                                 \
            f32x2 u1 = S0 * wgo[0] + ggo;                                       \
            f32x2 u2 = S1 * wgo[1] + S2 * wgo[2];                               \
            f32x2 u3 = S3 * wgo[3] + S4 * wgo[4];                               \
            ggo = u1 + u2 + u3;                                                 \
            float si = fsig(gif.x);                                             \
            float sf = fsig(gif.y);                                             \
            float tg = ftanh(ggo.x);                                            \
            float so = fsig(ggo.y);                                             \
            cm = fmaf(sf, cm, si * tg);                                         \
            hm = so * ftanh(cm);                                                \
            if (EMIT) hs[(size_t)(base + l0 + (j)) * 5 + m] = hm;               \
            s0 = bcast(hm, 0); s1 = bcast(hm, 1); s2 = bcast(hm, 2);            \
            s3 = bcast(hm, 3); s4 = bcast(hm, 4);                               \
        }

    int l0 = 0;
    for (; l0 < skip; l0 += 16) {
        #pragma unroll
        for (int j = 0; j < 16; ++j) LSTM_STEP(j, false)
    }
    for (; l0 < nsteps; l0 += 16) {
        #pragma unroll
        for (int j = 0; j < 16; ++j) LSTM_STEP(j, true)
    }
    #undef LSTM_STEP
}

// ============================================================================
// final / auxiliary heads
// ============================================================================
__global__ __launch_bounds__(256) void final_kernel(
    const float* __restrict__ lstm_in, const float* __restrict__ hs,
    const float* __restrict__ Wt, const float* __restrict__ bt,
    const float* __restrict__ Wa, const float* __restrict__ ba,
    float* __restrict__ out)
{
    const int l = blockIdx.x * 256 + threadIdx.x;
    float f[14];
    #pragma unroll
    for (int j = 0; j < 9; ++j) f[j] = lstm_in[(size_t)l * 9 + j];
    #pragma unroll
    for (int j = 0; j < 5; ++j) f[9 + j] = hs[(size_t)l * 5 + j];
    #pragma unroll
    for (int c = 0; c < 2; ++c) {
        float a = bt[c], b = ba[c];
        #pragma unroll
        for (int j = 0; j < 14; ++j) {
            a = fmaf(f[j], Wt[j * 2 + c], a);
            b = fmaf(f[j], Wa[j * 2 + c], b);
        }
        out[(size_t)l * 2 + c]         = a;
        out[16384 + (size_t)l * 2 + c] = b;
    }
}

// ============================================================================
extern "C" void kernel_launch(void* const* d_in, const int* in_sizes, int n_in,
                              void* d_out, int out_size, void* d_ws, size_t ws_size,
                              hipStream_t stream)
{
    const float* text   = (const float*)d_in[0];
    const float* prices = (const float*)d_in[1];
    const float* pos    = (const float*)d_in[2];
    const float* Wq1    = (const float*)d_in[3];
    const float* Wk1    = (const float*)d_in[4];
    const float* Wv1    = (const float*)d_in[5];
    const float* Wo1    = (const float*)d_in[6];
    const float* ln_g   = (const float*)d_in[7];
    const float* ln_b   = (const float*)d_in[8];
    const float* W1     = (const float*)d_in[9];
    const float* b1     = (const float*)d_in[10];
    const float* W2     = (const float*)d_in[11];
    const float* b2     = (const float*)d_in[12];
    const float* Wq2    = (const float*)d_in[13];
    const float* Wk2    = (const float*)d_in[14];
    const float* Wv2    = (const float*)d_in[15];
    const float* Wo2    = (const float*)d_in[16];
    const float* w_u    = (const float*)d_in[17];
    const float* w_m    = (const float*)d_in[18];
    const float* Wih    = (const float*)d_in[19];
    const float* Whh    = (const float*)d_in[20];
    const float* bih    = (const float*)d_in[21];
    const float* bhh    = (const float*)d_in[22];
    const float* Wt     = (const float*)d_in[23];
    const float* bt     = (const float*)d_in[24];
    const float* Wa     = (const float*)d_in[25];
    const float* ba     = (const float*)d_in[26];

    float* ws = (float*)d_ws;
    const size_t BUF = (size_t)NROW * DIMD;         // 33,554,432 elems / buffer
    const size_t MW  = (size_t)DIMD * DIMD;         // 1,048,576
    float* A = ws;
    float* B = ws + BUF;
    float* C = ws + 2 * BUF;
    float* F0   = ws + 3 * BUF;                     // fp32 MW scratch
    float* F1   = F0 + MW;                          // fp32 MW scratch
    float* attL = F1 + MW;                          // legacy 1024 slot
    float* U    = attL + 1024;                      // union: prob | lstm area
    float* prob    = U;                             // LAG*4*16*4 = 2,097,152
    float* lstm_in = U;
    float* pre     = lstm_in + (size_t)LAG * 9;
    float* hs      = pre + ((size_t)LAG * 20 + 400);
    uint_t* Wpk    = (uint_t*)(U + 2097152);        // 8 x MW slots (plane pairs)
    float* out     = (float*)d_out;

    const size_t need_base = ((size_t)(3 * BUF) + 2 * MW + 1024 + 2097152) * 4;
    const size_t need_full = need_base + 8 * MW * 4;
    const bool full = ws_size >= need_full;

    uint_t* Ap = (uint_t*)A;
    uint_t* Bp = (uint_t*)B;
    uint_t* Cp = (uint_t*)C;

    // plane views of big buffers (full path): hi plane, then lo plane
    ushort_t* Axh = (ushort_t*)A;  ushort_t* Axl = Axh + BUF;
    ushort_t* Bxh = (ushort_t*)B;  ushort_t* Bxl = Bxh + BUF;
    ushort_t* Cxh = (ushort_t*)C;  ushort_t* Cxl = Cxh + BUF;

    // weight slots: each MW uints = hi plane (MW ushorts) + lo plane (MW ushorts)
    uint_t* S0 = Wpk + 0 * MW;  uint_t* S1 = Wpk + 1 * MW;
    uint_t* S2 = Wpk + 2 * MW;  uint_t* S3 = Wpk + 3 * MW;
    uint_t* S4 = Wpk + 4 * MW;  uint_t* S6 = Wpk + 6 * MW;
    uint_t* S7 = Wpk + 7 * MW;
#define PH(s) ((ushort_t*)(s))
#define PL(s) ((ushort_t*)(s) + MW)
    float* vecs = full ? (float*)(Wpk + 5 * MW) : (float*)Wpk;
    float* attS  = vecs;
    float* tmpS  = vecs + 1024;
    float* wvec  = vecs + 2048;
    float* wvec2 = vecs + 3072;
    float* w_a   = vecs + 4096;
    float* w_b   = vecs + 5120;
    float* vv    = vecs + 6144;
    float* czv   = vecs + 7168;
    float* partS = vecs + 8192;

    dim3 gbig(4, 128), gsml(4, 4), gblk8(512);      // gemm8 grids
    dim3 ggrid(8, 256), gblk(256);                  // fallback mgemm
    dim3 pgrid(8, 8);

    // --- small-vector precomputes ---
    att_kernel<<<1, 1024, 0, stream>>>(w_u, w_m, attS);
    mv_kernel<<<256, 256, 0, stream>>>(Wo2, attS, tmpS);           // Wo2 @ att
    mv_kernel<<<256, 256, 0, stream>>>(Wv2, tmpS, wvec);           // wvec = Wv2@Wo2@att
    mv_kernel<<<256, 256, 0, stream>>>(W2, wvec, wvec2);           // wvec2 = W2 @ wvec
    dot_kernel<<<1, 1024, 0, stream>>>(b2, wvec, czv);             // cz = b2 · wvec
    mvt_part_kernel<<<16, 1024, 0, stream>>>(Wq2, b2, partS);      // w_a = Wq2^T @ b2
    mvt_red_kernel<<<4, 256, 0, stream>>>(partS, w_a);
    mv_kernel<<<256, 256, 0, stream>>>(Wk2, w_a, w_b);             // w_b = Wk2 @ w_a
    mv_kernel<<<256, 256, 0, stream>>>(W2, w_b, vv);               // v = W2 @ w_b

    if (full) {
        splitx2<<<32768, 256, 0, stream>>>(text, pos, Axh, Axl);   // x planes

        // weight prep (all products via gemm8; B-side always transposed planes)
        splitw2 <<<1024, 256, 0, stream>>>(W2,  PH(S6), PL(S6));
        splitwt2<<<256, 256, 0, stream>>>(Wq2, PH(S7), PL(S7));
        gemm8<0,false,false><<<gsml, gblk8, 0, stream>>>(PH(S6), PL(S6), PH(S7), PL(S7),
                                                         nullptr, F0, nullptr, nullptr); // E = W2@Wq2
        splitwt2<<<256, 256, 0, stream>>>(Wk2, PH(S7), PL(S7));
        gemm8<0,false,false><<<gsml, gblk8, 0, stream>>>(PH(S6), PL(S6), PH(S7), PL(S7),
                                                         nullptr, F1, nullptr, nullptr); // F = W2@Wk2
        splitw2<<<1024, 256, 0, stream>>>(F0, PH(S6), PL(S6));     // E planes
        splitw2<<<1024, 256, 0, stream>>>(F1, PH(S7), PL(S7));     // F planes (Bt of F^T)
        gemm8<0,false,false><<<gsml, gblk8, 0, stream>>>(PH(S6), PL(S6), PH(S7), PL(S7),
                                                         nullptr, F0, nullptr, nullptr); // Wss = E@F^T
        splitwt2<<<256, 256, 0, stream>>>(F0, PH(S3), PL(S3));     // Wss^T planes
        splitw2 <<<1024, 256, 0, stream>>>(Wv1, PH(S6), PL(S6));
        splitwt2<<<256, 256, 0, stream>>>(Wo1, PH(S7), PL(S7));
        gemm8<0,false,false><<<gsml, gblk8, 0, stream>>>(PH(S6), PL(S6), PH(S7), PL(S7),
                                                         nullptr, F1, nullptr, nullptr); // Wvo1 = Wv1@Wo1
        splitwt2<<<256, 256, 0, stream>>>(F1, PH(S4), PL(S4));     // Wvo1^T planes
        splitwt2<<<256, 256, 0, stream>>>(Wq1, PH(S0), PL(S0));
        splitwt2<<<256, 256, 0, stream>>>(Wk1, PH(S1), PL(S1));
        splitwt2<<<256, 256, 0, stream>>>(W1,  PH(S2), PL(S2));

        // big pipeline (5 GEMMs on the 256^2 deep-pipelined kernel)
        gemm8<1,false,false><<<gbig, gblk8, 0, stream>>>(Axh, Axl, PH(S0), PL(S0),
                                                         nullptr, nullptr, Bxh, Bxl);   // q
        gemm8<1,false,false><<<gbig, gblk8, 0, stream>>>(Axh, Axl, PH(S1), PL(S1),
                                                         nullptr, nullptr, Cxh, Cxl);   // k
        score2<<<LAG, 256, 0, stream>>>(Bxh, Bxl, Cxh, Cxl, prob);
        gemm8<1,false,false><<<gbig, gblk8, 0, stream>>>(Axh, Axl, PH(S4), PL(S4),
                                                         nullptr, nullptr, Bxh, Bxl);   // vmat (q dead)
        mixln2<<<LAG, 256, 0, stream>>>(Bxh, Bxl, prob, text, pos, ln_g, ln_b,
                                        Cxh, Cxl);                                       // y (k dead)
        gemm8<1,true ,true ><<<gbig, gblk8, 0, stream>>>(Cxh, Cxl, PH(S2), PL(S2),
                                                         b1, nullptr, Bxh, Bxl);        // relu (vmat dead)
        gemm8<0,true ,false><<<gbig, gblk8, 0, stream>>>(Bxh, Bxl, PH(S3), PL(S3),
                                                         vv, A, nullptr, nullptr);      // tt = relu@Wss+v (x dead)
        attn2out2<<<LAG, 256, 0, stream>>>(Bxh, Bxl, A, wvec2, czv, prices,
                                           Wih, bih, bhh, lstm_in, pre);
    } else {
        splitx_kernel<<<32768, 256, 0, stream>>>(text, pos, Ap);
        gemm_f32<false><<<pgrid, gblk, 0, stream>>>(W2, Wq2, U);            // E
        gemm_f32<false><<<pgrid, gblk, 0, stream>>>(W2, Wk2, U + MW);       // F
        gemm_f32<true ><<<pgrid, gblk, 0, stream>>>(U, U + MW, F0);         // Wss
        gemm_f32<false><<<pgrid, gblk, 0, stream>>>(Wv1, Wo1, F1);          // Wvo1

        mgemm<0,1,false,false><<<ggrid, gblk, 0, stream>>>(Ap, Wq1, nullptr, nullptr, Bp);
        mgemm<0,1,false,false><<<ggrid, gblk, 0, stream>>>(Ap, Wk1, nullptr, nullptr, Cp);
        score_kernel<<<LAG, 256, 0, stream>>>(Bp, Cp, prob);
        mgemm<0,1,false,false><<<ggrid, gblk, 0, stream>>>(Ap, F1,  nullptr, nullptr, Bp);
        mixln_kernel<<<LAG, 256, 0, stream>>>(Bp, prob, text, pos, ln_g, ln_b, Cp);
        mgemm<0,1,true ,true ><<<ggrid, gblk, 0, stream>>>(Cp, W1,  b1, nullptr, Bp);
        mgemm<0,0,true ,false><<<ggrid, gblk, 0, stream>>>(Bp, F0,  vv, A, nullptr);
        attn2out_kernel<<<LAG, 256, 0, stream>>>(Bp, A, wvec2, czv, prices,
                                                 Wih, bih, bhh, lstm_in, pre);
    }

    lstm_kernel <<<32, 64, 0, stream>>>(pre, Whh, hs);
    final_kernel<<<32, 256, 0, stream>>>(lstm_in, hs, Wt, bt, Wa, ba, out);
}